// Round 1
// baseline (29695.859 us; speedup 1.0000x reference)
//
#include <hip/hip_runtime.h>
#include <math.h>

#define B_    2
#define S_    2048
#define H_    2048
#define NH_   16
#define NOPE_ 128
#define ROPE_ 64
#define VDIM_ 128
#define RANK_ 512
#define QHD_  192   // NOPE + ROPE

// ---------------------------------------------------------------------------
// Generic fp32 GEMM: C[M,N] = A[M,K] @ B[K,N], row-major, all dims %64==0,
// K%16==0. 64x64 block tile, 256 threads, 4x4 per thread.
// ---------------------------------------------------------------------------
__global__ __launch_bounds__(256) void sgemm64(const float* __restrict__ A,
                                               const float* __restrict__ B,
                                               float* __restrict__ C,
                                               int M, int N, int K)
{
    __shared__ float As[16][64];   // [k][m] (transposed on store)
    __shared__ float Bs[16][64];   // [k][n]
    const int t  = threadIdx.x;
    const int tx = t & 15;         // 0..15 -> 4 cols each
    const int ty = t >> 4;         // 0..15 -> 4 rows each
    const int rowBase = blockIdx.y * 64;
    const int colBase = blockIdx.x * 64;
    const int ar = t >> 2;         // 0..63 row within A tile
    const int ac = (t & 3) << 2;   // 0,4,8,12 col within A tile
    const int br = t >> 4;         // 0..15 row within B tile
    const int bc = (t & 15) << 2;  // 0..60 col within B tile

    float acc[4][4] = {};

    for (int k0 = 0; k0 < K; k0 += 16) {
        float4 av = *(const float4*)(A + (size_t)(rowBase + ar) * K + k0 + ac);
        float4 bv = *(const float4*)(B + (size_t)(k0 + br) * N + colBase + bc);
        As[ac + 0][ar] = av.x;
        As[ac + 1][ar] = av.y;
        As[ac + 2][ar] = av.z;
        As[ac + 3][ar] = av.w;
        *(float4*)(&Bs[br][bc]) = bv;
        __syncthreads();
#pragma unroll
        for (int k = 0; k < 16; ++k) {
            float a0 = As[k][ty * 4 + 0], a1 = As[k][ty * 4 + 1];
            float a2 = As[k][ty * 4 + 2], a3 = As[k][ty * 4 + 3];
            float b0 = Bs[k][tx * 4 + 0], b1 = Bs[k][tx * 4 + 1];
            float b2 = Bs[k][tx * 4 + 2], b3 = Bs[k][tx * 4 + 3];
            acc[0][0] += a0 * b0; acc[0][1] += a0 * b1; acc[0][2] += a0 * b2; acc[0][3] += a0 * b3;
            acc[1][0] += a1 * b0; acc[1][1] += a1 * b1; acc[1][2] += a1 * b2; acc[1][3] += a1 * b3;
            acc[2][0] += a2 * b0; acc[2][1] += a2 * b1; acc[2][2] += a2 * b2; acc[2][3] += a2 * b3;
            acc[3][0] += a3 * b0; acc[3][1] += a3 * b1; acc[3][2] += a3 * b2; acc[3][3] += a3 * b3;
        }
        __syncthreads();
    }
#pragma unroll
    for (int i = 0; i < 4; ++i) {
        float4 v = make_float4(acc[i][0], acc[i][1], acc[i][2], acc[i][3]);
        *(float4*)(C + (size_t)(rowBase + ty * 4 + i) * N + colBase + tx * 4) = v;
    }
}

// ---------------------------------------------------------------------------
// Per-(b,s) row: RMSNorm the first 512 of ckv_full, RoPE the last 64 -> kpe.
// 128 threads/block, grid = B*S.
// ---------------------------------------------------------------------------
__global__ __launch_bounds__(128) void postkv(const float* __restrict__ ckv_full,
                                              const float* __restrict__ lnw,
                                              const int*   __restrict__ pos_ids,
                                              const float* __restrict__ cosc,
                                              const float* __restrict__ sinc,
                                              float* __restrict__ ckv_norm,
                                              float* __restrict__ kpe_rot)
{
    const int row = blockIdx.x;       // b*S + s
    const int t   = threadIdx.x;      // 0..127
    const float* src = ckv_full + (size_t)row * (RANK_ + ROPE_);
    __shared__ float red[128];

    float4 v = *(const float4*)(src + t * 4);
    float ss = v.x * v.x + v.y * v.y + v.z * v.z + v.w * v.w;
    red[t] = ss;
    __syncthreads();
    for (int off = 64; off > 0; off >>= 1) {
        if (t < off) red[t] += red[t + off];
        __syncthreads();
    }
    const float rs = rsqrtf(red[0] / (float)RANK_ + 1e-6f);

    float* dst = ckv_norm + (size_t)row * RANK_;
    dst[t * 4 + 0] = v.x * rs * lnw[t * 4 + 0];
    dst[t * 4 + 1] = v.y * rs * lnw[t * 4 + 1];
    dst[t * 4 + 2] = v.z * rs * lnw[t * 4 + 2];
    dst[t * 4 + 3] = v.w * rs * lnw[t * 4 + 3];

    if (t < 32) {
        const int pos = pos_ids[row];
        const float c  = cosc[pos * ROPE_ + t];
        const float sn = sinc[pos * ROPE_ + t];
        const float x0 = src[RANK_ + 2 * t];
        const float x1 = src[RANK_ + 2 * t + 1];
        kpe_rot[(size_t)row * ROPE_ + t]      = x0 * c - x1 * sn;
        kpe_rot[(size_t)row * ROPE_ + 32 + t] = x1 * c + x0 * sn;
    }
}

// ---------------------------------------------------------------------------
// RoPE q_pe in place for all heads. grid = B*S, 512 threads (16 heads x 32).
// ---------------------------------------------------------------------------
__global__ __launch_bounds__(512) void ropeq(float* __restrict__ q_buf,
                                             const int*   __restrict__ pos_ids,
                                             const float* __restrict__ cosc,
                                             const float* __restrict__ sinc)
{
    const int row = blockIdx.x;       // b*S + s
    const int t   = threadIdx.x;
    const int h   = t >> 5;           // 0..15
    const int i   = t & 31;           // 0..31
    const int pos = pos_ids[row];
    const float c  = cosc[pos * ROPE_ + i];
    const float sn = sinc[pos * ROPE_ + i];
    float* qrow = q_buf + (size_t)row * (NH_ * QHD_) + h * QHD_ + NOPE_;
    const float x0 = qrow[2 * i];
    const float x1 = qrow[2 * i + 1];
    __syncthreads();
    qrow[i]      = x0 * c - x1 * sn;
    qrow[32 + i] = x1 * c + x0 * sn;
}

// ---------------------------------------------------------------------------
// Attention: one block per (b,h,q) row. Computes q_nope_c on the fly,
// scores over k<=q (causal), softmax, x = p @ ckv, attn = x @ out_absorb^T.
// ---------------------------------------------------------------------------
__global__ __launch_bounds__(256) void attn_row(const float* __restrict__ q_buf,
                                                const float* __restrict__ ckv,
                                                const float* __restrict__ kpe,
                                                const float* __restrict__ Wkv_b,
                                                float* __restrict__ attn_buf)
{
    __shared__ float qp_s[ROPE_];
    __shared__ float qn_s[NOPE_];
    __shared__ float qc_s[RANK_];
    __shared__ float xb[RANK_];
    __shared__ float red[256];
    __shared__ float sc[S_];

    const int t = threadIdx.x;
    int idx = blockIdx.x;
    const int q = idx % S_;  idx /= S_;
    const int h = idx % NH_; idx /= NH_;
    const int b = idx;

    const float* qrow = q_buf + (size_t)(b * S_ + q) * (NH_ * QHD_) + h * QHD_;
    if (t < NOPE_) qn_s[t] = qrow[t];
    if (t >= NOPE_ && t < QHD_) qp_s[t - NOPE_] = qrow[t];
    __syncthreads();

    // q_nope_c[c] = sum_d q_nope[d] * Wkv_b[h, d, c]
    for (int cc = t; cc < RANK_; cc += 256) {
        const float* qa = Wkv_b + (size_t)h * 256 * RANK_ + cc;
        float a = 0.f;
#pragma unroll 8
        for (int d = 0; d < NOPE_; ++d) a += qn_s[d] * qa[(size_t)d * RANK_];
        qc_s[cc] = a;
    }
    __syncthreads();

    const float scale = 1.0f / sqrtf((float)QHD_);

    // scores for k <= q
    float lmax = -1e30f;
    for (int k = t; k <= q; k += 256) {
        const float* kp = kpe + ((size_t)b * S_ + k) * ROPE_;
        const float* cv = ckv + ((size_t)b * S_ + k) * RANK_;
        float s = 0.f;
#pragma unroll 8
        for (int i = 0; i < ROPE_; ++i) s += qp_s[i] * kp[i];
#pragma unroll 8
        for (int c = 0; c < RANK_; ++c) s += qc_s[c] * cv[c];
        s *= scale;
        sc[k] = s;
        lmax = fmaxf(lmax, s);
    }
    red[t] = lmax;
    __syncthreads();
    for (int off = 128; off > 0; off >>= 1) {
        if (t < off) red[t] = fmaxf(red[t], red[t + off]);
        __syncthreads();
    }
    const float m = red[0];
    __syncthreads();

    float lsum = 0.f;
    for (int k = t; k <= q; k += 256) {
        float e = expf(sc[k] - m);
        sc[k] = e;
        lsum += e;
    }
    red[t] = lsum;
    __syncthreads();
    for (int off = 128; off > 0; off >>= 1) {
        if (t < off) red[t] += red[t + off];
        __syncthreads();
    }
    const float inv_d = 1.0f / red[0];
    __syncthreads();

    // x[c] = (sum_k e_k * ckv[k,c]) * inv_d
    for (int cc = t; cc < RANK_; cc += 256) {
        const float* cv = ckv + (size_t)b * S_ * RANK_ + cc;
        float a = 0.f;
        for (int k = 0; k <= q; ++k) a += sc[k] * cv[(size_t)k * RANK_];
        xb[cc] = a * inv_d;
    }
    __syncthreads();

    // attn[d] = sum_c x[c] * Wkv_b[h, 128 + d, c]
    if (t < VDIM_) {
        const float* ob = Wkv_b + ((size_t)h * 256 + NOPE_ + t) * RANK_;
        float a = 0.f;
#pragma unroll 8
        for (int c = 0; c < RANK_; ++c) a += xb[c] * ob[c];
        attn_buf[((size_t)(b * S_ + q)) * (NH_ * VDIM_) + h * VDIM_ + t] = a;
    }
}

extern "C" void kernel_launch(void* const* d_in, const int* in_sizes, int n_in,
                              void* d_out, int out_size, void* d_ws, size_t ws_size,
                              hipStream_t stream)
{
    const float* hidden  = (const float*)d_in[0];
    // d_in[1] = attention_mask: guaranteed causal tril -> handled analytically
    const int*   pos_ids = (const int*)d_in[2];
    const float* cosc    = (const float*)d_in[3];
    const float* sinc    = (const float*)d_in[4];
    const float* Wq      = (const float*)d_in[5];
    const float* Wkv_a   = (const float*)d_in[6];
    const float* lnw     = (const float*)d_in[7];
    const float* Wkv_b   = (const float*)d_in[8];
    const float* Wo      = (const float*)d_in[9];
    float* out = (float*)d_out;

    const int M = B_ * S_;                       // 4096
    float* ws       = (float*)d_ws;
    float* q_buf    = ws;                                    // M * 3072
    float* ckv_full = q_buf    + (size_t)M * (NH_ * QHD_);   // M * 576
    float* ckv_norm = ckv_full + (size_t)M * (RANK_ + ROPE_);// M * 512
    float* kpe_rot  = ckv_norm + (size_t)M * RANK_;          // M * 64
    float* attn_buf = kpe_rot  + (size_t)M * ROPE_;          // M * 2048

    // 1. q = hidden @ Wq
    sgemm64<<<dim3((NH_ * QHD_) / 64, M / 64), 256, 0, stream>>>(
        hidden, Wq, q_buf, M, NH_ * QHD_, H_);
    // 2. ckv_full = hidden @ Wkv_a
    sgemm64<<<dim3((RANK_ + ROPE_) / 64, M / 64), 256, 0, stream>>>(
        hidden, Wkv_a, ckv_full, M, RANK_ + ROPE_, H_);
    // 3. RMSNorm + k_pe RoPE
    postkv<<<M, 128, 0, stream>>>(ckv_full, lnw, pos_ids, cosc, sinc,
                                  ckv_norm, kpe_rot);
    // 4. q_pe RoPE in place
    ropeq<<<M, 512, 0, stream>>>(q_buf, pos_ids, cosc, sinc);
    // 5. attention rows
    attn_row<<<B_ * NH_ * S_, 256, 0, stream>>>(q_buf, ckv_norm, kpe_rot,
                                                Wkv_b, attn_buf);
    // 6. out = attn @ Wo
    sgemm64<<<dim3(H_ / 64, M / 64), 256, 0, stream>>>(
        attn_buf, Wo, out, M, H_, H_);
}

// Round 2
// 3410.563 us; speedup vs baseline: 8.7070x; 8.7070x over previous
//
#include <hip/hip_runtime.h>
#include <math.h>

#define B_    2
#define S_    2048
#define H_    2048
#define NH_   16
#define NOPE_ 128
#define ROPE_ 64
#define VDIM_ 128
#define RANK_ 512
#define QHD_  192   // NOPE + ROPE
#define DTOT_ 576   // RANK + ROPE

typedef short short8 __attribute__((ext_vector_type(8)));
typedef float f32x4 __attribute__((ext_vector_type(4)));

__device__ __forceinline__ unsigned short f2bf(float f) {
    unsigned u = __float_as_uint(f);
    u += 0x7fffu + ((u >> 16) & 1u);
    return (unsigned short)(u >> 16);
}
__device__ __forceinline__ unsigned long long pack4bf(float a, float b, float c, float d) {
    return (unsigned long long)f2bf(a) | ((unsigned long long)f2bf(b) << 16) |
           ((unsigned long long)f2bf(c) << 32) | ((unsigned long long)f2bf(d) << 48);
}

// ---------------------------------------------------------------------------
// Generic fp32 GEMM: C[M,N] = A[M,K] @ B[K,N], row-major, dims %64, K%16.
// ---------------------------------------------------------------------------
__global__ __launch_bounds__(256) void sgemm64(const float* __restrict__ A,
                                               const float* __restrict__ B,
                                               float* __restrict__ C,
                                               int M, int N, int K)
{
    __shared__ float As[16][64];
    __shared__ float Bs[16][64];
    const int t  = threadIdx.x;
    const int tx = t & 15;
    const int ty = t >> 4;
    const int rowBase = blockIdx.y * 64;
    const int colBase = blockIdx.x * 64;
    const int ar = t >> 2;
    const int ac = (t & 3) << 2;
    const int br = t >> 4;
    const int bc = (t & 15) << 2;

    float acc[4][4] = {};
    for (int k0 = 0; k0 < K; k0 += 16) {
        float4 av = *(const float4*)(A + (size_t)(rowBase + ar) * K + k0 + ac);
        float4 bv = *(const float4*)(B + (size_t)(k0 + br) * N + colBase + bc);
        As[ac + 0][ar] = av.x; As[ac + 1][ar] = av.y;
        As[ac + 2][ar] = av.z; As[ac + 3][ar] = av.w;
        *(float4*)(&Bs[br][bc]) = bv;
        __syncthreads();
#pragma unroll
        for (int k = 0; k < 16; ++k) {
            float a0 = As[k][ty*4+0], a1 = As[k][ty*4+1], a2 = As[k][ty*4+2], a3 = As[k][ty*4+3];
            float b0 = Bs[k][tx*4+0], b1 = Bs[k][tx*4+1], b2 = Bs[k][tx*4+2], b3 = Bs[k][tx*4+3];
            acc[0][0]+=a0*b0; acc[0][1]+=a0*b1; acc[0][2]+=a0*b2; acc[0][3]+=a0*b3;
            acc[1][0]+=a1*b0; acc[1][1]+=a1*b1; acc[1][2]+=a1*b2; acc[1][3]+=a1*b3;
            acc[2][0]+=a2*b0; acc[2][1]+=a2*b1; acc[2][2]+=a2*b2; acc[2][3]+=a2*b3;
            acc[3][0]+=a3*b0; acc[3][1]+=a3*b1; acc[3][2]+=a3*b2; acc[3][3]+=a3*b3;
        }
        __syncthreads();
    }
#pragma unroll
    for (int i = 0; i < 4; ++i) {
        float4 v = make_float4(acc[i][0], acc[i][1], acc[i][2], acc[i][3]);
        *(float4*)(C + (size_t)(rowBase + ty*4 + i) * N + colBase + tx*4) = v;
    }
}

// ---------------------------------------------------------------------------
// q_nope_c GEMM per (b,h): q_cat[b,h,q,0:512] = bf16( q_nope[b,q,h,:] @ q_absorb[h] )
// grid (512/64, 2048/64, B*NH); A strided (lda=3072), B = Wkv_b[h][0:128][512].
// ---------------------------------------------------------------------------
__global__ __launch_bounds__(256) void qc_gemm(const float* __restrict__ qb,
                                               const float* __restrict__ wb,
                                               unsigned short* __restrict__ q_cat)
{
    __shared__ float As[16][64];
    __shared__ float Bs[16][64];
    const int t  = threadIdx.x;
    const int tx = t & 15;
    const int ty = t >> 4;
    const int h  = blockIdx.z & 15;
    const int b  = blockIdx.z >> 4;
    const int q0 = blockIdx.y * 64;
    const int c0 = blockIdx.x * 64;
    const int ar = t >> 2;
    const int ac = (t & 3) << 2;
    const int br = t >> 4;
    const int bc = (t & 15) << 2;

    const float* A = qb + (size_t)b * S_ * (NH_*QHD_) + h * QHD_;        // row stride 3072
    const float* Bm = wb + (size_t)h * 256 * RANK_;                       // rows d, stride 512

    float acc[4][4] = {};
    for (int k0 = 0; k0 < NOPE_; k0 += 16) {
        float4 av = *(const float4*)(A + (size_t)(q0 + ar) * (NH_*QHD_) + k0 + ac);
        float4 bv = *(const float4*)(Bm + (size_t)(k0 + br) * RANK_ + c0 + bc);
        As[ac + 0][ar] = av.x; As[ac + 1][ar] = av.y;
        As[ac + 2][ar] = av.z; As[ac + 3][ar] = av.w;
        *(float4*)(&Bs[br][bc]) = bv;
        __syncthreads();
#pragma unroll
        for (int k = 0; k < 16; ++k) {
            float a0 = As[k][ty*4+0], a1 = As[k][ty*4+1], a2 = As[k][ty*4+2], a3 = As[k][ty*4+3];
            float b0 = Bs[k][tx*4+0], b1 = Bs[k][tx*4+1], b2 = Bs[k][tx*4+2], b3 = Bs[k][tx*4+3];
            acc[0][0]+=a0*b0; acc[0][1]+=a0*b1; acc[0][2]+=a0*b2; acc[0][3]+=a0*b3;
            acc[1][0]+=a1*b0; acc[1][1]+=a1*b1; acc[1][2]+=a1*b2; acc[1][3]+=a1*b3;
            acc[2][0]+=a2*b0; acc[2][1]+=a2*b1; acc[2][2]+=a2*b2; acc[2][3]+=a2*b3;
            acc[3][0]+=a3*b0; acc[3][1]+=a3*b1; acc[3][2]+=a3*b2; acc[3][3]+=a3*b3;
        }
        __syncthreads();
    }
#pragma unroll
    for (int i = 0; i < 4; ++i) {
        size_t row = ((size_t)(b * NH_ + h) * S_ + q0 + ty*4 + i);
        *(unsigned long long*)(q_cat + row * DTOT_ + c0 + tx*4) =
            pack4bf(acc[i][0], acc[i][1], acc[i][2], acc[i][3]);
    }
}

// ---------------------------------------------------------------------------
// Per (b,s) row: RMSNorm ckv -> k_cat[0:512] bf16; RoPE k_pe -> k_cat[512:576].
// ---------------------------------------------------------------------------
__global__ __launch_bounds__(128) void postkv(const float* __restrict__ ckv_full,
                                              const float* __restrict__ lnw,
                                              const int*   __restrict__ pos_ids,
                                              const float* __restrict__ cosc,
                                              const float* __restrict__ sinc,
                                              unsigned short* __restrict__ k_cat)
{
    const int row = blockIdx.x;
    const int t   = threadIdx.x;
    const float* src = ckv_full + (size_t)row * DTOT_;
    __shared__ float red[128];

    float4 v = *(const float4*)(src + t * 4);
    red[t] = v.x*v.x + v.y*v.y + v.z*v.z + v.w*v.w;
    __syncthreads();
    for (int off = 64; off > 0; off >>= 1) {
        if (t < off) red[t] += red[t + off];
        __syncthreads();
    }
    const float rs = rsqrtf(red[0] / (float)RANK_ + 1e-6f);

    unsigned short* kc = k_cat + (size_t)row * DTOT_;
    *(unsigned long long*)(kc + t*4) =
        pack4bf(v.x*rs*lnw[t*4+0], v.y*rs*lnw[t*4+1], v.z*rs*lnw[t*4+2], v.w*rs*lnw[t*4+3]);

    if (t < 32) {
        const int pos = pos_ids[row];
        const float c  = cosc[pos * ROPE_ + t];
        const float sn = sinc[pos * ROPE_ + t];
        const float x0 = src[RANK_ + 2*t];
        const float x1 = src[RANK_ + 2*t + 1];
        kc[RANK_ + t]      = f2bf(x0*c - x1*sn);
        kc[RANK_ + 32 + t] = f2bf(x1*c + x0*sn);
    }
}

// ---------------------------------------------------------------------------
// RoPE q_pe -> q_cat[...,512:576] bf16. grid = B*S, 512 threads (16 heads x 32).
// ---------------------------------------------------------------------------
__global__ __launch_bounds__(512) void ropeq(const float* __restrict__ q_buf,
                                             const int*   __restrict__ pos_ids,
                                             const float* __restrict__ cosc,
                                             const float* __restrict__ sinc,
                                             unsigned short* __restrict__ q_cat)
{
    const int row = blockIdx.x;       // b*S + s
    const int t   = threadIdx.x;
    const int h   = t >> 5;
    const int i   = t & 31;
    const int pos = pos_ids[row];
    const float c  = cosc[pos * ROPE_ + i];
    const float sn = sinc[pos * ROPE_ + i];
    const float* qrow = q_buf + (size_t)row * (NH_*QHD_) + h * QHD_ + NOPE_;
    const float x0 = qrow[2*i];
    const float x1 = qrow[2*i + 1];
    const int b = row >> 11, s = row & 2047;
    unsigned short* qc = q_cat + ((size_t)(b * NH_ + h) * S_ + s) * DTOT_ + RANK_;
    qc[i]      = f2bf(x0*c - x1*sn);
    qc[32 + i] = f2bf(x1*c + x0*sn);
}

// ---------------------------------------------------------------------------
// Vt[b,c,k] = k_cat[b,k,c] for c<512 (bf16 transpose, 64x64 tiles).
// grid (2048/64, 512/64, B), 256 threads.
// ---------------------------------------------------------------------------
__global__ __launch_bounds__(256) void transpose_v(const unsigned short* __restrict__ k_cat,
                                                   unsigned short* __restrict__ vt)
{
    __shared__ unsigned short tl[64][72];
    const int t  = threadIdx.x;
    const int k0 = blockIdx.x * 64;
    const int c0 = blockIdx.y * 64;
    const int b  = blockIdx.z;
    const int lr = t >> 4;            // 0..15
    const int lc = (t & 15) * 4;      // 0..60
#pragma unroll
    for (int r = 0; r < 4; ++r) {
        const unsigned short* src = k_cat + ((size_t)b * S_ + k0 + lr*4 + r) * DTOT_ + c0 + lc;
        ushort4 v = *(const ushort4*)src;
        tl[lr*4 + r][lc+0] = v.x; tl[lr*4 + r][lc+1] = v.y;
        tl[lr*4 + r][lc+2] = v.z; tl[lr*4 + r][lc+3] = v.w;
    }
    __syncthreads();
#pragma unroll
    for (int r = 0; r < 4; ++r) {
        ushort4 v;
        v.x = tl[lc+0][lr*4+r]; v.y = tl[lc+1][lr*4+r];
        v.z = tl[lc+2][lr*4+r]; v.w = tl[lc+3][lr*4+r];
        *(ushort4*)(vt + ((size_t)b * RANK_ + c0 + lr*4 + r) * S_ + k0 + lc) = v;
    }
}

// ---------------------------------------------------------------------------
// Cast Wkv_b fp32 -> bf16 (all 16*256*512 elements).
// ---------------------------------------------------------------------------
__global__ __launch_bounds__(256) void wcast(const float* __restrict__ w,
                                             unsigned short* __restrict__ wbf)
{
    const size_t i = ((size_t)blockIdx.x * 256 + threadIdx.x) * 4;
    float4 v = *(const float4*)(w + i);
    *(unsigned long long*)(wbf + i) = pack4bf(v.x, v.y, v.z, v.w);
}

// ---------------------------------------------------------------------------
// Flash attention: 1 wave per block, 16 q-rows per wave, K-tiles of 32.
// S^T = K @ Q^T via mfma (A=K rows, B=Q rows, both row-major over c).
// PV: X^T = V^T @ P^T (A from Vt rows, B=P from LDS).
// Epilogue: attn = X @ out_absorb^T via mfma, coalesced fp32 stores.
// ---------------------------------------------------------------------------
__global__ __launch_bounds__(64, 2) void flash_attn(
    const unsigned short* __restrict__ q_cat,
    const unsigned short* __restrict__ k_cat,
    const unsigned short* __restrict__ vt,
    const unsigned short* __restrict__ w2bf,
    float* __restrict__ attn_buf)
{
    __shared__ __align__(16) unsigned short plds[16][40];   // P [q][kk], pad to 40
    __shared__ __align__(16) unsigned short xlds[16][520];  // X [q][c],  pad to 520

    const int lane = threadIdx.x;
    const int lq   = lane & 15;
    const int quad = lane >> 4;
    const int q0   = blockIdx.x * 16;
    const int h    = blockIdx.y;
    const int b    = blockIdx.z;

    const unsigned short* qrow = q_cat + (((size_t)(b*NH_ + h)) * S_ + q0 + lq) * DTOT_ + quad*8;
    const unsigned short* kb   = k_cat + ((size_t)b * S_ + lq) * DTOT_ + quad*8;
    const unsigned short* vb   = vt    + ((size_t)b * RANK_ + lq) * S_ + quad*8;

    f32x4 o[32];
#pragma unroll
    for (int i = 0; i < 32; ++i) o[i] = (f32x4){0.f, 0.f, 0.f, 0.f};
    float m_i = -1e30f, l_i = 0.f;
    const float scale = 0.0721687836f;  // 1/sqrt(192)
    const int myq = q0 + lq;
    const int ntiles = (q0 + 16 + 31) >> 5;

    for (int t = 0; t < ntiles; ++t) {
        const int k0 = t << 5;
        f32x4 s0 = {0.f,0.f,0.f,0.f}, s1 = {0.f,0.f,0.f,0.f};
        const unsigned short* kr = kb + (size_t)k0 * DTOT_;
#pragma unroll
        for (int c = 0; c < 18; ++c) {
            short8 qf  = *(const short8*)(qrow + c*32);
            short8 ka0 = *(const short8*)(kr + c*32);
            short8 ka1 = *(const short8*)(kr + (size_t)16*DTOT_ + c*32);
            s0 = __builtin_amdgcn_mfma_f32_16x16x32_bf16(ka0, qf, s0, 0, 0, 0);
            s1 = __builtin_amdgcn_mfma_f32_16x16x32_bf16(ka1, qf, s1, 0, 0, 0);
        }
        float sv[8];
#pragma unroll
        for (int r = 0; r < 4; ++r) {
            int kk0 = k0 + quad*4 + r;
            sv[r]     = (kk0      <= myq) ? s0[r]*scale : -1e30f;
            sv[r + 4] = (kk0 + 16 <= myq) ? s1[r]*scale : -1e30f;
        }
        float mx = sv[0];
#pragma unroll
        for (int i = 1; i < 8; ++i) mx = fmaxf(mx, sv[i]);
        mx = fmaxf(mx, __shfl_xor(mx, 16));
        mx = fmaxf(mx, __shfl_xor(mx, 32));
        const float m_new = fmaxf(m_i, mx);
        const float alpha = __expf(m_i - m_new);
        float p[8]; float ls = 0.f;
#pragma unroll
        for (int i = 0; i < 8; ++i) { p[i] = __expf(sv[i] - m_new); ls += p[i]; }
        ls += __shfl_xor(ls, 16);
        ls += __shfl_xor(ls, 32);
        l_i = l_i * alpha + ls; m_i = m_new;
        if (__any(alpha < 1.0f)) {
#pragma unroll
            for (int i = 0; i < 32; ++i) {
                o[i][0]*=alpha; o[i][1]*=alpha; o[i][2]*=alpha; o[i][3]*=alpha;
            }
        }
        // P^T (C-layout) -> plds as P[q][kk] (regs r are 4 consecutive kk)
        *(unsigned long long*)&plds[lq][quad*4]      = pack4bf(p[0], p[1], p[2], p[3]);
        *(unsigned long long*)&plds[lq][16 + quad*4] = pack4bf(p[4], p[5], p[6], p[7]);
        __syncthreads();
        short8 pb = *(const short8*)&plds[lq][quad*8];
        const unsigned short* vr = vb + k0;
#pragma unroll
        for (int ct = 0; ct < 32; ++ct) {
            short8 va = *(const short8*)(vr + (size_t)ct * 16 * S_);
            o[ct] = __builtin_amdgcn_mfma_f32_16x16x32_bf16(va, pb, o[ct], 0, 0, 0);
        }
        __syncthreads();
    }

    const float inv = 1.0f / l_i;
#pragma unroll
    for (int i = 0; i < 32; ++i) {
        *(unsigned long long*)&xlds[lq][i*16 + quad*4] =
            pack4bf(o[i][0]*inv, o[i][1]*inv, o[i][2]*inv, o[i][3]*inv);
    }
    __syncthreads();

    f32x4 acc[8];
#pragma unroll
    for (int i = 0; i < 8; ++i) acc[i] = (f32x4){0.f, 0.f, 0.f, 0.f};
    const unsigned short* wrow = w2bf + ((size_t)h*256 + NOPE_ + lq) * RANK_ + quad*8;
#pragma unroll
    for (int cc = 0; cc < 16; ++cc) {
        short8 xa = *(const short8*)&xlds[lq][cc*32 + quad*8];
#pragma unroll
        for (int dt = 0; dt < 8; ++dt) {
            short8 wf = *(const short8*)(wrow + (size_t)dt*16*RANK_ + cc*32);
            acc[dt] = __builtin_amdgcn_mfma_f32_16x16x32_bf16(xa, wf, acc[dt], 0, 0, 0);
        }
    }
    float* orow = attn_buf + ((size_t)b * S_ + q0 + quad*4) * (NH_*VDIM_) + h*VDIM_ + lq;
#pragma unroll
    for (int dt = 0; dt < 8; ++dt)
#pragma unroll
        for (int r = 0; r < 4; ++r)
            orow[(size_t)r * (NH_*VDIM_) + dt*16] = acc[dt][r];
}

extern "C" void kernel_launch(void* const* d_in, const int* in_sizes, int n_in,
                              void* d_out, int out_size, void* d_ws, size_t ws_size,
                              hipStream_t stream)
{
    const float* hidden  = (const float*)d_in[0];
    // d_in[1] = attention_mask (guaranteed causal tril, handled analytically)
    const int*   pos_ids = (const int*)d_in[2];
    const float* cosc    = (const float*)d_in[3];
    const float* sinc    = (const float*)d_in[4];
    const float* Wq      = (const float*)d_in[5];
    const float* Wkv_a   = (const float*)d_in[6];
    const float* lnw     = (const float*)d_in[7];
    const float* Wkv_b   = (const float*)d_in[8];
    const float* Wo      = (const float*)d_in[9];
    float* out = (float*)d_out;

    const int M = B_ * S_;  // 4096
    char* ws = (char*)d_ws;
    float* q_buf             = (float*)ws;                         // 4096*3072 f32 = 50.3MB
    float* attn_buf          = q_buf;                              // alias (dead by then)
    char*  p                 = ws + (size_t)M * (NH_*QHD_) * 4;
    float* ckv_full          = (float*)p;  p += (size_t)M * DTOT_ * 4;        // 9.4MB
    unsigned short* q_cat    = (unsigned short*)p; p += (size_t)M*NH_*DTOT_*2; // 75.5MB
    unsigned short* k_cat    = (unsigned short*)p; p += (size_t)M * DTOT_ * 2; // 4.7MB
    unsigned short* vt       = (unsigned short*)p; p += (size_t)B_*RANK_*S_*2; // 4.2MB
    unsigned short* w2bf     = (unsigned short*)p;                             // 4.2MB

    // 1. q = hidden @ Wq
    sgemm64<<<dim3((NH_*QHD_)/64, M/64), 256, 0, stream>>>(hidden, Wq, q_buf, M, NH_*QHD_, H_);
    // 2. ckv_full = hidden @ Wkv_a
    sgemm64<<<dim3(DTOT_/64, M/64), 256, 0, stream>>>(hidden, Wkv_a, ckv_full, M, DTOT_, H_);
    // 3. RMSNorm + k_pe RoPE -> k_cat (bf16)
    postkv<<<M, 128, 0, stream>>>(ckv_full, lnw, pos_ids, cosc, sinc, k_cat);
    // 4. q_pe RoPE -> q_cat[...,512:576] (bf16)
    ropeq<<<M, 512, 0, stream>>>(q_buf, pos_ids, cosc, sinc, q_cat);
    // 5. Vt = transpose of k_cat[:, :512]
    transpose_v<<<dim3(S_/64, RANK_/64, B_), 256, 0, stream>>>(k_cat, vt);
    // 6. Wkv_b -> bf16
    wcast<<<(NH_*256*RANK_)/1024, 256, 0, stream>>>(Wkv_b, w2bf);
    // 7. q_cat[...,0:512] = q_nope @ q_absorb (bf16)
    qc_gemm<<<dim3(RANK_/64, S_/64, B_*NH_), 256, 0, stream>>>(q_buf, Wkv_b, q_cat);
    // 8. flash attention -> attn_buf (aliases q_buf; q_buf fully consumed by now)
    flash_attn<<<dim3(S_/16, NH_, B_), 64, 0, stream>>>(q_cat, k_cat, vt, w2bf, attn_buf);
    // 9. out = attn @ Wo
    sgemm64<<<dim3(H_/64, M/64), 256, 0, stream>>>(attn_buf, Wo, out, M, H_, H_);
}

// Round 3
// 1998.480 us; speedup vs baseline: 14.8592x; 1.7066x over previous
//
#include <hip/hip_runtime.h>
#include <math.h>

#define B_    2
#define S_    2048
#define H_    2048
#define NH_   16
#define NOPE_ 128
#define ROPE_ 64
#define VDIM_ 128
#define RANK_ 512
#define QHD_  192   // NOPE + ROPE
#define DTOT_ 576   // RANK + ROPE

typedef short short8 __attribute__((ext_vector_type(8)));
typedef float f32x4 __attribute__((ext_vector_type(4)));

__device__ __forceinline__ unsigned short f2bf(float f) {
    unsigned u = __float_as_uint(f);
    u += 0x7fffu + ((u >> 16) & 1u);
    return (unsigned short)(u >> 16);
}
__device__ __forceinline__ unsigned pack2bf(float a, float b) {
    return (unsigned)f2bf(a) | ((unsigned)f2bf(b) << 16);
}
__device__ __forceinline__ unsigned long long pack4bf(float a, float b, float c, float d) {
    return (unsigned long long)pack2bf(a, b) | ((unsigned long long)pack2bf(c, d) << 32);
}
union i4s8 { int4 i; short8 s; };

// ---------------------------------------------------------------------------
// Transpose + cast: in fp32 [Rr][Cc] (batched) -> out bf16 [Cc][Rr].
// grid (Rr/64, Cc/64, batch), 256 threads.
// ---------------------------------------------------------------------------
__global__ __launch_bounds__(256) void transpose_w(const float* __restrict__ in,
                                                   unsigned short* __restrict__ out,
                                                   int Rr, int Cc,
                                                   size_t inBatch, size_t outBatch)
{
    __shared__ unsigned short tl[64][72];
    in  += (size_t)blockIdx.z * inBatch;
    out += (size_t)blockIdx.z * outBatch;
    const int t  = threadIdx.x;
    const int r0 = blockIdx.x * 64;
    const int c0 = blockIdx.y * 64;
    const int lr = t >> 4;            // 0..15
    const int lc = (t & 15) * 4;      // 0..60
#pragma unroll
    for (int r = 0; r < 4; ++r) {
        float4 v = *(const float4*)(in + (size_t)(r0 + lr*4 + r) * Cc + c0 + lc);
        tl[lr*4 + r][lc+0] = f2bf(v.x); tl[lr*4 + r][lc+1] = f2bf(v.y);
        tl[lr*4 + r][lc+2] = f2bf(v.z); tl[lr*4 + r][lc+3] = f2bf(v.w);
    }
    __syncthreads();
#pragma unroll
    for (int r = 0; r < 4; ++r) {
        ushort4 v;
        v.x = tl[lc+0][lr*4+r]; v.y = tl[lc+1][lr*4+r];
        v.z = tl[lc+2][lr*4+r]; v.w = tl[lc+3][lr*4+r];
        *(ushort4*)(out + (size_t)(c0 + lr*4 + r) * Rr + r0 + lc) = v;
    }
}

// ---------------------------------------------------------------------------
// bf16 MFMA GEMM: C fp32[M][N](ldc) = A fp32[M][K](lda) @ Bt^T, Bt bf16 [N][K].
// Tile 128(M) x 64(N), K-step 32, 128 threads (2 waves; wave w owns 64 M-rows).
// ---------------------------------------------------------------------------
__global__ __launch_bounds__(128, 4) void bgemm(const float* __restrict__ A, int lda,
                                                const unsigned short* __restrict__ Bt,
                                                float* __restrict__ C, int ldc, int K)
{
    __shared__ unsigned short Asl[128][40];
    __shared__ unsigned short Bsl[64][40];
    const int t = threadIdx.x;
    const int w = t >> 6;
    const int lane = t & 63;
    const int lq = lane & 15, quad = lane >> 4;
    const int m0 = blockIdx.y * 128, n0 = blockIdx.x * 64;

    f32x4 acc[4][4] = {};
    for (int k0 = 0; k0 < K; k0 += 32) {
#pragma unroll
        for (int j = 0; j < 8; ++j) {
            int f = t + 128*j;
            int row = f >> 3, kg = f & 7;
            float4 v = *(const float4*)(A + (size_t)(m0 + row) * lda + k0 + kg*4);
            *(unsigned long long*)&Asl[row][kg*4] = pack4bf(v.x, v.y, v.z, v.w);
        }
#pragma unroll
        for (int j = 0; j < 2; ++j) {
            int f = t + 128*j;
            int row = f >> 2, kg = f & 3;
            short8 v = *(const short8*)(Bt + (size_t)(n0 + row) * K + k0 + kg*8);
            *(short8*)&Bsl[row][kg*8] = v;
        }
        __syncthreads();
        short8 bfr[4];
#pragma unroll
        for (int ni = 0; ni < 4; ++ni) bfr[ni] = *(const short8*)&Bsl[ni*16 + lq][quad*8];
#pragma unroll
        for (int mi = 0; mi < 4; ++mi) {
            short8 afr = *(const short8*)&Asl[w*64 + mi*16 + lq][quad*8];
#pragma unroll
            for (int ni = 0; ni < 4; ++ni)
                acc[mi][ni] = __builtin_amdgcn_mfma_f32_16x16x32_bf16(afr, bfr[ni], acc[mi][ni], 0, 0, 0);
        }
        __syncthreads();
    }
#pragma unroll
    for (int mi = 0; mi < 4; ++mi)
#pragma unroll
        for (int ni = 0; ni < 4; ++ni)
#pragma unroll
            for (int r = 0; r < 4; ++r)
                C[(size_t)(m0 + w*64 + mi*16 + quad*4 + r) * ldc + n0 + ni*16 + lq] = acc[mi][ni][r];
}

// ---------------------------------------------------------------------------
// q_nope_c GEMM (bf16 MFMA): q_cat[z=b*16+h][q][0:512] = q_nope @ wqaT[h]^T.
// A = q_buf rows (lda 3072, col offset h*192), K=128. grid (8, 16, 32).
// ---------------------------------------------------------------------------
__global__ __launch_bounds__(128, 4) void qc_gemm2(const float* __restrict__ qb,
                                                   const unsigned short* __restrict__ wqaT,
                                                   unsigned short* __restrict__ q_cat)
{
    __shared__ unsigned short Asl[128][40];
    __shared__ unsigned short Bsl[64][40];
    const int t = threadIdx.x;
    const int w = t >> 6;
    const int lane = t & 63;
    const int lq = lane & 15, quad = lane >> 4;
    const int m0 = blockIdx.y * 128, n0 = blockIdx.x * 64;
    const int z = blockIdx.z;
    const int h = z & 15, b = z >> 4;
    const float* A = qb + ((size_t)b * S_) * (NH_*QHD_) + h * QHD_;
    const unsigned short* Bt = wqaT + (size_t)h * RANK_ * NOPE_;

    f32x4 acc[4][4] = {};
    for (int k0 = 0; k0 < NOPE_; k0 += 32) {
#pragma unroll
        for (int j = 0; j < 8; ++j) {
            int f = t + 128*j;
            int row = f >> 3, kg = f & 7;
            float4 v = *(const float4*)(A + (size_t)(m0 + row) * (NH_*QHD_) + k0 + kg*4);
            *(unsigned long long*)&Asl[row][kg*4] = pack4bf(v.x, v.y, v.z, v.w);
        }
#pragma unroll
        for (int j = 0; j < 2; ++j) {
            int f = t + 128*j;
            int row = f >> 2, kg = f & 3;
            short8 v = *(const short8*)(Bt + (size_t)(n0 + row) * NOPE_ + k0 + kg*8);
            *(short8*)&Bsl[row][kg*8] = v;
        }
        __syncthreads();
        short8 bfr[4];
#pragma unroll
        for (int ni = 0; ni < 4; ++ni) bfr[ni] = *(const short8*)&Bsl[ni*16 + lq][quad*8];
#pragma unroll
        for (int mi = 0; mi < 4; ++mi) {
            short8 afr = *(const short8*)&Asl[w*64 + mi*16 + lq][quad*8];
#pragma unroll
            for (int ni = 0; ni < 4; ++ni)
                acc[mi][ni] = __builtin_amdgcn_mfma_f32_16x16x32_bf16(afr, bfr[ni], acc[mi][ni], 0, 0, 0);
        }
        __syncthreads();
    }
#pragma unroll
    for (int mi = 0; mi < 4; ++mi)
#pragma unroll
        for (int ni = 0; ni < 4; ++ni)
#pragma unroll
            for (int r = 0; r < 4; ++r)
                q_cat[((size_t)z * S_ + m0 + w*64 + mi*16 + quad*4 + r) * DTOT_ + n0 + ni*16 + lq] =
                    f2bf(acc[mi][ni][r]);
}

// ---------------------------------------------------------------------------
// Per (b,s) row: RMSNorm ckv -> k_cat[0:512] bf16; RoPE k_pe -> k_cat[512:576].
// ---------------------------------------------------------------------------
__global__ __launch_bounds__(128) void postkv(const float* __restrict__ ckv_full,
                                              const float* __restrict__ lnw,
                                              const int*   __restrict__ pos_ids,
                                              const float* __restrict__ cosc,
                                              const float* __restrict__ sinc,
                                              unsigned short* __restrict__ k_cat)
{
    const int row = blockIdx.x;
    const int t   = threadIdx.x;
    const float* src = ckv_full + (size_t)row * DTOT_;
    __shared__ float red[128];

    float4 v = *(const float4*)(src + t * 4);
    red[t] = v.x*v.x + v.y*v.y + v.z*v.z + v.w*v.w;
    __syncthreads();
    for (int off = 64; off > 0; off >>= 1) {
        if (t < off) red[t] += red[t + off];
        __syncthreads();
    }
    const float rs = rsqrtf(red[0] / (float)RANK_ + 1e-6f);

    unsigned short* kc = k_cat + (size_t)row * DTOT_;
    *(unsigned long long*)(kc + t*4) =
        pack4bf(v.x*rs*lnw[t*4+0], v.y*rs*lnw[t*4+1], v.z*rs*lnw[t*4+2], v.w*rs*lnw[t*4+3]);

    if (t < 32) {
        const int pos = pos_ids[row];
        const float c  = cosc[pos * ROPE_ + t];
        const float sn = sinc[pos * ROPE_ + t];
        const float x0 = src[RANK_ + 2*t];
        const float x1 = src[RANK_ + 2*t + 1];
        kc[RANK_ + t]      = f2bf(x0*c - x1*sn);
        kc[RANK_ + 32 + t] = f2bf(x1*c + x0*sn);
    }
}

// ---------------------------------------------------------------------------
// RoPE q_pe -> q_cat[...,512:576] bf16. grid = B*S, 512 threads.
// ---------------------------------------------------------------------------
__global__ __launch_bounds__(512) void ropeq(const float* __restrict__ q_buf,
                                             const int*   __restrict__ pos_ids,
                                             const float* __restrict__ cosc,
                                             const float* __restrict__ sinc,
                                             unsigned short* __restrict__ q_cat)
{
    const int row = blockIdx.x;
    const int t   = threadIdx.x;
    const int h   = t >> 5;
    const int i   = t & 31;
    const int pos = pos_ids[row];
    const float c  = cosc[pos * ROPE_ + i];
    const float sn = sinc[pos * ROPE_ + i];
    const float* qrow = q_buf + (size_t)row * (NH_*QHD_) + h * QHD_ + NOPE_;
    const float x0 = qrow[2*i];
    const float x1 = qrow[2*i + 1];
    const int b = row >> 11, s = row & 2047;
    unsigned short* qc = q_cat + ((size_t)(b * NH_ + h) * S_ + s) * DTOT_ + RANK_;
    qc[i]      = f2bf(x0*c - x1*sn);
    qc[32 + i] = f2bf(x1*c + x0*sn);
}

// ---------------------------------------------------------------------------
// Vt[b,c,k] = k_cat[b,k,c] for c<512 (bf16 transpose). grid (32, 8, 2).
// ---------------------------------------------------------------------------
__global__ __launch_bounds__(256) void transpose_v(const unsigned short* __restrict__ k_cat,
                                                   unsigned short* __restrict__ vt)
{
    __shared__ unsigned short tl[64][72];
    const int t  = threadIdx.x;
    const int k0 = blockIdx.x * 64;
    const int c0 = blockIdx.y * 64;
    const int b  = blockIdx.z;
    const int lr = t >> 4;
    const int lc = (t & 15) * 4;
#pragma unroll
    for (int r = 0; r < 4; ++r) {
        ushort4 v = *(const ushort4*)(k_cat + ((size_t)b * S_ + k0 + lr*4 + r) * DTOT_ + c0 + lc);
        tl[lr*4 + r][lc+0] = v.x; tl[lr*4 + r][lc+1] = v.y;
        tl[lr*4 + r][lc+2] = v.z; tl[lr*4 + r][lc+3] = v.w;
    }
    __syncthreads();
#pragma unroll
    for (int r = 0; r < 4; ++r) {
        ushort4 v;
        v.x = tl[lc+0][lr*4+r]; v.y = tl[lc+1][lr*4+r];
        v.z = tl[lc+2][lr*4+r]; v.w = tl[lc+3][lr*4+r];
        *(ushort4*)(vt + ((size_t)b * RANK_ + c0 + lr*4 + r) * S_ + k0 + lc) = v;
    }
}

__global__ __launch_bounds__(256) void wcast(const float* __restrict__ w,
                                             unsigned short* __restrict__ wbf)
{
    const size_t i = ((size_t)blockIdx.x * 256 + threadIdx.x) * 4;
    float4 v = *(const float4*)(w + i);
    *(unsigned long long*)(wbf + i) = pack4bf(v.x, v.y, v.z, v.w);
}

// ---------------------------------------------------------------------------
// Flash attention v2: 1 wave/block, ZERO LDS, zero barriers.
// C-layout -> A-layout transforms done with ds_bpermute (__shfl) among the
// 4 lanes {lq, lq+16, lq+32, lq+48}. Longest q-strips dispatched first.
// ---------------------------------------------------------------------------
__device__ __forceinline__ short8 quad_transpose(unsigned d0, unsigned d1,
                                                 unsigned d2, unsigned d3,
                                                 int srcA, int srcB, bool lowquad)
{
    int e0 = __shfl((int)d0, srcA, 64);
    int e1 = __shfl((int)d1, srcA, 64);
    int e2 = __shfl((int)d2, srcA, 64);
    int e3 = __shfl((int)d3, srcA, 64);
    int f0 = __shfl((int)d0, srcB, 64);
    int f1 = __shfl((int)d1, srcB, 64);
    int f2 = __shfl((int)d2, srcB, 64);
    int f3 = __shfl((int)d3, srcB, 64);
    i4s8 u;
    u.i.x = lowquad ? e0 : e2;
    u.i.y = lowquad ? e1 : e3;
    u.i.z = lowquad ? f0 : f2;
    u.i.w = lowquad ? f1 : f3;
    return u.s;
}

__global__ __launch_bounds__(64, 2) void flash_attn(
    const unsigned short* __restrict__ q_cat,
    const unsigned short* __restrict__ k_cat,
    const unsigned short* __restrict__ vt,
    const unsigned short* __restrict__ w2bf,
    float* __restrict__ attn_buf)
{
    const int lane = threadIdx.x;
    const int lq   = lane & 15;
    const int quad = lane >> 4;
    const int h    = blockIdx.x;
    const int q0   = (127 - blockIdx.y) * 16;   // longest strips first
    const int b    = blockIdx.z;
    const int srcA = lq + ((quad & 1) << 5);
    const int srcB = srcA + 16;
    const bool lowq = quad < 2;

    const unsigned short* qrow = q_cat + (((size_t)(b*NH_ + h)) * S_ + q0 + lq) * DTOT_ + quad*8;
    short8 qf[18];
#pragma unroll
    for (int c = 0; c < 18; ++c) qf[c] = *(const short8*)(qrow + c*32);

    const unsigned short* kb = k_cat + ((size_t)b * S_ + lq) * DTOT_ + quad*8;
    const unsigned short* vb = vt    + ((size_t)b * RANK_ + lq) * S_ + quad*8;

    f32x4 o[32];
#pragma unroll
    for (int i = 0; i < 32; ++i) o[i] = (f32x4){0.f, 0.f, 0.f, 0.f};
    float m_i = -1e30f, l_i = 0.f;
    const float scale = 0.0721687836f;  // 1/sqrt(192)
    const int myq = q0 + lq;
    const int ntiles = (q0 + 47) >> 5;

    for (int t = 0; t < ntiles; ++t) {
        const int k0 = t << 5;
        f32x4 s0a = {0.f,0.f,0.f,0.f}, s0b = {0.f,0.f,0.f,0.f};
        f32x4 s1a = {0.f,0.f,0.f,0.f}, s1b = {0.f,0.f,0.f,0.f};
        const unsigned short* kr = kb + (size_t)k0 * DTOT_;
#pragma unroll
        for (int c = 0; c < 18; c += 2) {
            short8 ka0 = *(const short8*)(kr + c*32);
            short8 kb0 = *(const short8*)(kr + (c+1)*32);
            short8 ka1 = *(const short8*)(kr + (size_t)16*DTOT_ + c*32);
            short8 kb1 = *(const short8*)(kr + (size_t)16*DTOT_ + (c+1)*32);
            s0a = __builtin_amdgcn_mfma_f32_16x16x32_bf16(ka0, qf[c],   s0a, 0, 0, 0);
            s1a = __builtin_amdgcn_mfma_f32_16x16x32_bf16(ka1, qf[c],   s1a, 0, 0, 0);
            s0b = __builtin_amdgcn_mfma_f32_16x16x32_bf16(kb0, qf[c+1], s0b, 0, 0, 0);
            s1b = __builtin_amdgcn_mfma_f32_16x16x32_bf16(kb1, qf[c+1], s1b, 0, 0, 0);
        }
        float sv[8];
#pragma unroll
        for (int r = 0; r < 4; ++r) {
            int kk0 = k0 + quad*4 + r;
            sv[r]     = (kk0      <= myq) ? (s0a[r] + s0b[r]) * scale : -1e30f;
            sv[r + 4] = (kk0 + 16 <= myq) ? (s1a[r] + s1b[r]) * scale : -1e30f;
        }
        float mx = sv[0];
#pragma unroll
        for (int i = 1; i < 8; ++i) mx = fmaxf(mx, sv[i]);
        mx = fmaxf(mx, __shfl_xor(mx, 16));
        mx = fmaxf(mx, __shfl_xor(mx, 32));
        const float m_new = fmaxf(m_i, mx);
        const float alpha = __expf(m_i - m_new);
        float p[8]; float ls = 0.f;
#pragma unroll
        for (int i = 0; i < 8; ++i) { p[i] = __expf(sv[i] - m_new); ls += p[i]; }
        ls += __shfl_xor(ls, 16);
        ls += __shfl_xor(ls, 32);
        l_i = l_i * alpha + ls; m_i = m_new;
        if (__any(alpha < 1.0f)) {
#pragma unroll
            for (int i = 0; i < 32; ++i) {
                o[i][0]*=alpha; o[i][1]*=alpha; o[i][2]*=alpha; o[i][3]*=alpha;
            }
        }
        // P: C-layout (lane holds P[q=lq][k=quad*4+r, 16+quad*4+r]) -> A/B-frag
        short8 pb = quad_transpose(pack2bf(p[0], p[1]), pack2bf(p[2], p[3]),
                                   pack2bf(p[4], p[5]), pack2bf(p[6], p[7]),
                                   srcA, srcB, lowq);
        const unsigned short* vr = vb + k0;
#pragma unroll
        for (int ct = 0; ct < 32; ++ct) {
            short8 va = *(const short8*)(vr + (size_t)ct * 16 * S_);
            o[ct] = __builtin_amdgcn_mfma_f32_16x16x32_bf16(va, pb, o[ct], 0, 0, 0);
        }
    }

    const float inv = 1.0f / l_i;
    f32x4 acc[8];
#pragma unroll
    for (int i = 0; i < 8; ++i) acc[i] = (f32x4){0.f, 0.f, 0.f, 0.f};
    const unsigned short* wrow = w2bf + ((size_t)h*256 + NOPE_ + lq) * RANK_ + quad*8;
#pragma unroll
    for (int ch = 0; ch < 16; ++ch) {
        // lane holds X[q=lq][c = ch*32 + {quad*4+r, 16+quad*4+r}]
        short8 xa = quad_transpose(
            pack2bf(o[2*ch][0]*inv,   o[2*ch][1]*inv),
            pack2bf(o[2*ch][2]*inv,   o[2*ch][3]*inv),
            pack2bf(o[2*ch+1][0]*inv, o[2*ch+1][1]*inv),
            pack2bf(o[2*ch+1][2]*inv, o[2*ch+1][3]*inv),
            srcA, srcB, lowq);
#pragma unroll
        for (int dt = 0; dt < 8; ++dt) {
            short8 wf = *(const short8*)(wrow + (size_t)dt*16*RANK_ + ch*32);
            acc[dt] = __builtin_amdgcn_mfma_f32_16x16x32_bf16(xa, wf, acc[dt], 0, 0, 0);
        }
    }
    float* orow = attn_buf + ((size_t)b * S_ + q0 + quad*4) * (NH_*VDIM_) + h*VDIM_ + lq;
#pragma unroll
    for (int dt = 0; dt < 8; ++dt)
#pragma unroll
        for (int r = 0; r < 4; ++r)
            orow[(size_t)r * (NH_*VDIM_) + dt*16] = acc[dt][r];
}

extern "C" void kernel_launch(void* const* d_in, const int* in_sizes, int n_in,
                              void* d_out, int out_size, void* d_ws, size_t ws_size,
                              hipStream_t stream)
{
    const float* hidden  = (const float*)d_in[0];
    // d_in[1] = attention_mask (guaranteed causal tril, handled analytically)
    const int*   pos_ids = (const int*)d_in[2];
    const float* cosc    = (const float*)d_in[3];
    const float* sinc    = (const float*)d_in[4];
    const float* Wq      = (const float*)d_in[5];
    const float* Wkv_a   = (const float*)d_in[6];
    const float* lnw     = (const float*)d_in[7];
    const float* Wkv_b   = (const float*)d_in[8];
    const float* Wo      = (const float*)d_in[9];
    float* out = (float*)d_out;

    const int M = B_ * S_;  // 4096
    char* ws = (char*)d_ws;
    // Layout (142.1 MB total, with aliasing):
    float* q_buf   = (float*)ws;                         // 50,331,648 B; later attn_buf
    float* attn_buf = q_buf;
    char* p1 = ws + (size_t)50331648;
    float* ckv_full = (float*)p1;                        // 9,437,184 B; after postkv:
    unsigned short* vt   = (unsigned short*)p1;          //   vt 4,194,304 B
    unsigned short* w2bf = (unsigned short*)(p1 + 4194304); // w2bf 4,194,304 B
    char* p2 = p1 + 9437184;
    unsigned short* q_cat = (unsigned short*)p2;         // 75,497,472 B
    unsigned short* wT    = (unsigned short*)p2;         //   alias: WqT/WkvaT (pre) & WoT (post-flash)
    char* p3 = p2 + (size_t)75497472;
    unsigned short* k_cat = (unsigned short*)p3;         // 4,718,592 B
    char* p4 = p3 + 4718592;
    unsigned short* wqaT  = (unsigned short*)p4;         // 2,097,152 B

    // 1. WqT = (Wq)^T bf16 [3072][2048]
    transpose_w<<<dim3(32, 48, 1), 256, 0, stream>>>(Wq, wT, H_, NH_*QHD_, 0, 0);
    // 2. q_buf = hidden @ Wq
    bgemm<<<dim3((NH_*QHD_)/64, M/128), 128, 0, stream>>>(hidden, H_, wT, q_buf, NH_*QHD_, H_);
    // 3. WkvaT bf16 [576][2048]
    transpose_w<<<dim3(32, 9, 1), 256, 0, stream>>>(Wkv_a, wT, H_, DTOT_, 0, 0);
    // 4. ckv_full = hidden @ Wkv_a
    bgemm<<<dim3(DTOT_/64, M/128), 128, 0, stream>>>(hidden, H_, wT, ckv_full, DTOT_, H_);
    // 5. RMSNorm + k_pe RoPE -> k_cat
    postkv<<<M, 128, 0, stream>>>(ckv_full, lnw, pos_ids, cosc, sinc, k_cat);
    // 6. q_pe RoPE -> q_cat[...,512:576]
    ropeq<<<M, 512, 0, stream>>>(q_buf, pos_ids, cosc, sinc, q_cat);
    // 7. Vt = transpose of k_cat[:, :512]  (overwrites dead ckv_full)
    transpose_v<<<dim3(S_/64, RANK_/64, B_), 256, 0, stream>>>(k_cat, vt);
    // 8. Wkv_b -> bf16 (flash epilogue weights)
    wcast<<<(NH_*256*RANK_)/1024, 256, 0, stream>>>(Wkv_b, w2bf);
    // 9. wqaT[h] = (Wkv_b[h][0:128])^T bf16 [512][128]
    transpose_w<<<dim3(2, 8, 16), 256, 0, stream>>>(Wkv_b, wqaT, NOPE_, RANK_,
                                                    (size_t)256*RANK_, (size_t)RANK_*NOPE_);
    // 10. q_cat[...,0:512] = q_nope @ q_absorb (bf16 MFMA)
    qc_gemm2<<<dim3(RANK_/64, S_/128, B_*NH_), 128, 0, stream>>>(q_buf, wqaT, q_cat);
    // 11. flash attention -> attn_buf (aliases q_buf, fully consumed)
    flash_attn<<<dim3(NH_, S_/16, B_), 64, 0, stream>>>(q_cat, k_cat, vt, w2bf, attn_buf);
    // 12. WoT bf16 [2048][2048] (q_cat dead after flash)
    transpose_w<<<dim3(32, 32, 1), 256, 0, stream>>>(Wo, wT, H_, H_, 0, 0);
    // 13. out = attn @ Wo
    bgemm<<<dim3(H_/64, M/128), 128, 0, stream>>>(attn_buf, H_, wT, out, H_, H_);
}

// Round 4
// 665.925 us; speedup vs baseline: 44.5934x; 3.0011x over previous
//
#include <hip/hip_runtime.h>
#include <math.h>

#define B_    2
#define S_    2048
#define H_    2048
#define NH_   16
#define NOPE_ 128
#define ROPE_ 64
#define VDIM_ 128
#define RANK_ 512
#define QHD_  192   // NOPE + ROPE
#define DTOT_ 576   // RANK + ROPE

typedef short short8 __attribute__((ext_vector_type(8)));
typedef float f32x4 __attribute__((ext_vector_type(4)));

__device__ __forceinline__ unsigned short f2bf(float f) {
    unsigned u = __float_as_uint(f);
    u += 0x7fffu + ((u >> 16) & 1u);
    return (unsigned short)(u >> 16);
}
__device__ __forceinline__ float bf2f(unsigned short u) {
    return __uint_as_float((unsigned)u << 16);
}
__device__ __forceinline__ unsigned pack2bf(float a, float b) {
    return (unsigned)f2bf(a) | ((unsigned)f2bf(b) << 16);
}
__device__ __forceinline__ unsigned long long pack4bf(float a, float b, float c, float d) {
    return (unsigned long long)pack2bf(a, b) | ((unsigned long long)pack2bf(c, d) << 32);
}
union i4s8 { int4 i; short8 s; };

// Async global->LDS, 16B per lane. LDS dest = wave-uniform base + lane*16.
typedef __attribute__((address_space(3))) unsigned int lds_u32_t;
typedef __attribute__((address_space(1))) const unsigned int glob_u32_t;
__device__ __forceinline__ void async_copy16(const unsigned short* g, unsigned short* l) {
    __builtin_amdgcn_global_load_lds((glob_u32_t*)g, (lds_u32_t*)l, 16, 0, 0);
}

// ---------------------------------------------------------------------------
// cast fp32 -> bf16, 4 elems/thread.
// ---------------------------------------------------------------------------
__global__ __launch_bounds__(256) void cast_bf16(const float* __restrict__ in,
                                                 unsigned short* __restrict__ out)
{
    const size_t i = ((size_t)blockIdx.x * 256 + threadIdx.x) * 4;
    float4 v = *(const float4*)(in + i);
    *(unsigned long long*)(out + i) = pack4bf(v.x, v.y, v.z, v.w);
}

// ---------------------------------------------------------------------------
// Transpose + cast: in fp32 [Rr][Cc] (batched) -> out bf16 [Cc][Rr].
// grid (Rr/64, Cc/64, batch), 256 threads.
// ---------------------------------------------------------------------------
__global__ __launch_bounds__(256) void transpose_w(const float* __restrict__ in,
                                                   unsigned short* __restrict__ out,
                                                   int Rr, int Cc,
                                                   size_t inBatch, size_t outBatch)
{
    __shared__ unsigned short tl[64][72];
    in  += (size_t)blockIdx.z * inBatch;
    out += (size_t)blockIdx.z * outBatch;
    const int t  = threadIdx.x;
    const int r0 = blockIdx.x * 64;
    const int c0 = blockIdx.y * 64;
    const int lr = t >> 4;
    const int lc = (t & 15) * 4;
#pragma unroll
    for (int r = 0; r < 4; ++r) {
        float4 v = *(const float4*)(in + (size_t)(r0 + lr*4 + r) * Cc + c0 + lc);
        tl[lr*4 + r][lc+0] = f2bf(v.x); tl[lr*4 + r][lc+1] = f2bf(v.y);
        tl[lr*4 + r][lc+2] = f2bf(v.z); tl[lr*4 + r][lc+3] = f2bf(v.w);
    }
    __syncthreads();
#pragma unroll
    for (int r = 0; r < 4; ++r) {
        ushort4 v;
        v.x = tl[lc+0][lr*4+r]; v.y = tl[lc+1][lr*4+r];
        v.z = tl[lc+2][lr*4+r]; v.w = tl[lc+3][lr*4+r];
        *(ushort4*)(out + (size_t)(c0 + lr*4 + r) * Rr + r0 + lc) = v;
    }
}

// ---------------------------------------------------------------------------
// bf16 MFMA GEMM, m97-style: C = A[M][K](lda) @ Bt^T, Bt bf16 [N][K].
// 128x128 tile, 4 waves, BK=32, global_load_lds staging. N-guard for ragged N.
// qcmode: per-z offsets for the q_nope@q_absorb batched GEMM.
// ---------------------------------------------------------------------------
#define BGEMM_BODY(STORE_STMT, CTYPE)                                              \
    __shared__ unsigned short Al[128*32];                                          \
    __shared__ unsigned short Bl[128*32];                                          \
    const int t = threadIdx.x;                                                     \
    const int wv = t >> 6;                                                         \
    const int lane = t & 63;                                                       \
    const int lq = lane & 15, quad = lane >> 4;                                    \
    const int m0 = blockIdx.y * 128, n0 = blockIdx.x * 128;                        \
    const int wrow = (wv >> 1) * 64, wcol = (wv & 1) * 64;                         \
    const int srow = lane >> 2;                                                    \
    const int scol = (lane & 3) * 8;                                               \
    f32x4 acc[4][4] = {};                                                          \
    for (int k0 = 0; k0 < K; k0 += 32) {                                           \
        _Pragma("unroll")                                                          \
        for (int pA = 0; pA < 2; ++pA) {                                           \
            const unsigned short* src =                                            \
                A + (size_t)(m0 + pA*64 + wv*16 + srow) * lda + k0 + scol;         \
            async_copy16(src, &Al[pA*2048 + wv*512]);                              \
        }                                                                          \
        _Pragma("unroll")                                                          \
        for (int pB = 0; pB < 2; ++pB) {                                           \
            int brow = n0 + pB*64 + wv*16 + srow;                                  \
            if (brow > N - 1) brow = N - 1;                                        \
            const unsigned short* src = B + (size_t)brow * K + k0 + scol;          \
            async_copy16(src, &Bl[pB*2048 + wv*512]);                              \
        }                                                                          \
        __syncthreads();                                                           \
        short8 af[4], bf[4];                                                       \
        _Pragma("unroll")                                                          \
        for (int i = 0; i < 4; ++i) {                                              \
            af[i] = *(const short8*)&Al[(wrow + i*16 + lq)*32 + quad*8];           \
            bf[i] = *(const short8*)&Bl[(wcol + i*16 + lq)*32 + quad*8];           \
        }                                                                          \
        _Pragma("unroll")                                                          \
        for (int mi = 0; mi < 4; ++mi)                                             \
            _Pragma("unroll")                                                      \
            for (int ni = 0; ni < 4; ++ni)                                         \
                acc[mi][ni] = __builtin_amdgcn_mfma_f32_16x16x32_bf16(             \
                    af[mi], bf[ni], acc[mi][ni], 0, 0, 0);                         \
        __syncthreads();                                                           \
    }                                                                              \
    _Pragma("unroll")                                                              \
    for (int mi = 0; mi < 4; ++mi)                                                 \
        _Pragma("unroll")                                                          \
        for (int ni = 0; ni < 4; ++ni) {                                           \
            int col = n0 + wcol + ni*16 + lq;                                      \
            if (col < N) {                                                         \
                _Pragma("unroll")                                                  \
                for (int r = 0; r < 4; ++r)                                        \
                    STORE_STMT;                                                    \
            }                                                                      \
        }

__global__ __launch_bounds__(256, 2) void bgemm2(const unsigned short* __restrict__ A,
                                                 int lda,
                                                 const unsigned short* __restrict__ B,
                                                 unsigned short* __restrict__ C,
                                                 int ldc, int K, int N, int qcmode)
{
    if (qcmode) {
        const int z = blockIdx.z;
        A += (size_t)(z >> 4) * S_ * (NH_*QHD_) + (z & 15) * QHD_;
        B += (size_t)(z & 15) * RANK_ * NOPE_;
        C += (size_t)z * S_ * DTOT_;
    }
    BGEMM_BODY(C[(size_t)(m0 + wrow + mi*16 + quad*4 + r) * ldc + col] = f2bf(acc[mi][ni][r]),
               unsigned short)
}

__global__ __launch_bounds__(256, 2) void bgemm2f(const unsigned short* __restrict__ A,
                                                  int lda,
                                                  const unsigned short* __restrict__ B,
                                                  float* __restrict__ C,
                                                  int ldc, int K, int N)
{
    BGEMM_BODY(C[(size_t)(m0 + wrow + mi*16 + quad*4 + r) * ldc + col] = acc[mi][ni][r],
               float)
}

// ---------------------------------------------------------------------------
// Per (b,s) row: RMSNorm ckv (bf16 in) -> k_cat[0:512]; RoPE k_pe -> [512:576].
// ---------------------------------------------------------------------------
__global__ __launch_bounds__(128) void postkv(const unsigned short* __restrict__ ckv_bf,
                                              const float* __restrict__ lnw,
                                              const int*   __restrict__ pos_ids,
                                              const float* __restrict__ cosc,
                                              const float* __restrict__ sinc,
                                              unsigned short* __restrict__ k_cat)
{
    const int row = blockIdx.x;
    const int t   = threadIdx.x;
    const unsigned short* src = ckv_bf + (size_t)row * DTOT_;
    __shared__ float red[128];

    ushort4 v = *(const ushort4*)(src + t * 4);
    float x0 = bf2f(v.x), x1 = bf2f(v.y), x2 = bf2f(v.z), x3 = bf2f(v.w);
    red[t] = x0*x0 + x1*x1 + x2*x2 + x3*x3;
    __syncthreads();
    for (int off = 64; off > 0; off >>= 1) {
        if (t < off) red[t] += red[t + off];
        __syncthreads();
    }
    const float rs = rsqrtf(red[0] / (float)RANK_ + 1e-6f);

    unsigned short* kc = k_cat + (size_t)row * DTOT_;
    *(unsigned long long*)(kc + t*4) =
        pack4bf(x0*rs*lnw[t*4+0], x1*rs*lnw[t*4+1], x2*rs*lnw[t*4+2], x3*rs*lnw[t*4+3]);

    if (t < 32) {
        const int pos = pos_ids[row];
        const float c  = cosc[pos * ROPE_ + t];
        const float sn = sinc[pos * ROPE_ + t];
        const float y0 = bf2f(src[RANK_ + 2*t]);
        const float y1 = bf2f(src[RANK_ + 2*t + 1]);
        kc[RANK_ + t]      = f2bf(y0*c - y1*sn);
        kc[RANK_ + 32 + t] = f2bf(y1*c + y0*sn);
    }
}

// ---------------------------------------------------------------------------
// RoPE q_pe (bf16 in) -> q_cat[...,512:576]. grid = B*S, 512 threads.
// ---------------------------------------------------------------------------
__global__ __launch_bounds__(512) void ropeq(const unsigned short* __restrict__ q_bf,
                                             const int*   __restrict__ pos_ids,
                                             const float* __restrict__ cosc,
                                             const float* __restrict__ sinc,
                                             unsigned short* __restrict__ q_cat)
{
    const int row = blockIdx.x;
    const int t   = threadIdx.x;
    const int h   = t >> 5;
    const int i   = t & 31;
    const int pos = pos_ids[row];
    const float c  = cosc[pos * ROPE_ + i];
    const float sn = sinc[pos * ROPE_ + i];
    const unsigned short* qrow = q_bf + (size_t)row * (NH_*QHD_) + h * QHD_ + NOPE_;
    const float x0 = bf2f(qrow[2*i]);
    const float x1 = bf2f(qrow[2*i + 1]);
    const int b = row >> 11, s = row & 2047;
    unsigned short* qc = q_cat + ((size_t)(b * NH_ + h) * S_ + s) * DTOT_ + RANK_;
    qc[i]      = f2bf(x0*c - x1*sn);
    qc[32 + i] = f2bf(x1*c + x0*sn);
}

// ---------------------------------------------------------------------------
// Vt[b,c,k] = k_cat[b,k,c] for c<512. grid (32, 8, 2).
// ---------------------------------------------------------------------------
__global__ __launch_bounds__(256) void transpose_v(const unsigned short* __restrict__ k_cat,
                                                   unsigned short* __restrict__ vt)
{
    __shared__ unsigned short tl[64][72];
    const int t  = threadIdx.x;
    const int k0 = blockIdx.x * 64;
    const int c0 = blockIdx.y * 64;
    const int b  = blockIdx.z;
    const int lr = t >> 4;
    const int lc = (t & 15) * 4;
#pragma unroll
    for (int r = 0; r < 4; ++r) {
        ushort4 v = *(const ushort4*)(k_cat + ((size_t)b * S_ + k0 + lr*4 + r) * DTOT_ + c0 + lc);
        tl[lr*4 + r][lc+0] = v.x; tl[lr*4 + r][lc+1] = v.y;
        tl[lr*4 + r][lc+2] = v.z; tl[lr*4 + r][lc+3] = v.w;
    }
    __syncthreads();
#pragma unroll
    for (int r = 0; r < 4; ++r) {
        ushort4 v;
        v.x = tl[lc+0][lr*4+r]; v.y = tl[lc+1][lr*4+r];
        v.z = tl[lc+2][lr*4+r]; v.w = tl[lc+3][lr*4+r];
        *(ushort4*)(vt + ((size_t)b * RANK_ + c0 + lr*4 + r) * S_ + k0 + lc) = v;
    }
}

__global__ __launch_bounds__(256) void wcast(const float* __restrict__ w,
                                             unsigned short* __restrict__ wbf)
{
    const size_t i = ((size_t)blockIdx.x * 256 + threadIdx.x) * 4;
    float4 v = *(const float4*)(w + i);
    *(unsigned long long*)(wbf + i) = pack4bf(v.x, v.y, v.z, v.w);
}

// ---------------------------------------------------------------------------
// Flash attention v3: 4 waves/block, 64 q-rows, K-tile 32 shared in LDS.
// Phase A: LDS = K-tile [32][584] (padded, manual stage) for QK^T.
// Phase B: LDS = Vt-tile [512][32] (global_load_lds) for PV.
// In-register C->A layout transform via quad shuffles (as R2/R3).
// ---------------------------------------------------------------------------
__device__ __forceinline__ short8 quad_transpose(unsigned d0, unsigned d1,
                                                 unsigned d2, unsigned d3,
                                                 int srcA, int srcB, bool lowquad)
{
    int e0 = __shfl((int)d0, srcA, 64);
    int e1 = __shfl((int)d1, srcA, 64);
    int e2 = __shfl((int)d2, srcA, 64);
    int e3 = __shfl((int)d3, srcA, 64);
    int f0 = __shfl((int)d0, srcB, 64);
    int f1 = __shfl((int)d1, srcB, 64);
    int f2 = __shfl((int)d2, srcB, 64);
    int f3 = __shfl((int)d3, srcB, 64);
    i4s8 u;
    u.i.x = lowquad ? e0 : e2;
    u.i.y = lowquad ? e1 : e3;
    u.i.z = lowquad ? f0 : f2;
    u.i.w = lowquad ? f1 : f3;
    return u.s;
}

__global__ __launch_bounds__(256, 2) void flash_attn3(
    const unsigned short* __restrict__ q_cat,
    const unsigned short* __restrict__ k_cat,
    const unsigned short* __restrict__ vt,
    const unsigned short* __restrict__ w2bf,
    unsigned short* __restrict__ attn_bf)
{
    __shared__ unsigned short sbuf[18688];  // A: K[32][584]=37376B; B: Vt[512][32]=32768B

    const int t    = threadIdx.x;
    const int wv   = t >> 6;
    const int lane = t & 63;
    const int lq   = lane & 15;
    const int quad = lane >> 4;
    const int h    = blockIdx.x;
    const int q0   = (31 - blockIdx.y) * 64;   // longest strips first
    const int b    = blockIdx.z;
    const int srcA = lq + ((quad & 1) << 5);
    const int srcB = srcA + 16;
    const bool lowq = quad < 2;
    const int myq  = q0 + wv*16 + lq;

    // Q fragments (loop-invariant)
    const unsigned short* qrow =
        q_cat + (((size_t)(b*NH_ + h)) * S_ + q0 + wv*16 + lq) * DTOT_ + quad*8;
    short8 qf[18];
#pragma unroll
    for (int c = 0; c < 18; ++c) qf[c] = *(const short8*)(qrow + c*32);

    const unsigned short* kcb = k_cat + (size_t)b * S_ * DTOT_;
    const unsigned short* vtb = vt    + (size_t)b * RANK_ * S_;

    f32x4 o[32];
#pragma unroll
    for (int i = 0; i < 32; ++i) o[i] = (f32x4){0.f, 0.f, 0.f, 0.f};
    float m_i = -1e30f, l_i = 0.f;
    const float scale = 0.0721687836f;  // 1/sqrt(192)
    const int ntiles = (q0 >> 5) + 2;

    // staging coords
    const int krow = t >> 3;             // 0..31
    const int kcol = (t & 7) * 8;        // shorts
    const int vrow = wv*16 + (lane >> 2);// + p*64
    const int vcol = (lane & 3) * 8;     // shorts
    unsigned short* ldsK = &sbuf[krow*584 + kcol];

    for (int tt = 0; tt < ntiles; ++tt) {
        const int k0 = tt << 5;
        __syncthreads();  // prev-iter Vt reads complete
        {   // Phase A stage: K rows k0..k0+31, padded rows (584 shorts)
            const unsigned short* ksrc = kcb + (size_t)(k0 + krow) * DTOT_ + kcol;
#pragma unroll 3
            for (int p = 0; p < 9; ++p)
                *(short8*)(ldsK + p*64) = *(const short8*)(ksrc + p*64);
        }
        __syncthreads();
        // QK^T
        f32x4 s0a = {0.f,0.f,0.f,0.f}, s0b = {0.f,0.f,0.f,0.f};
        f32x4 s1a = {0.f,0.f,0.f,0.f}, s1b = {0.f,0.f,0.f,0.f};
#pragma unroll
        for (int c = 0; c < 18; c += 2) {
            short8 ka0 = *(const short8*)&sbuf[lq*584      + c*32     + quad*8];
            short8 kb0 = *(const short8*)&sbuf[lq*584      + (c+1)*32 + quad*8];
            short8 ka1 = *(const short8*)&sbuf[(16+lq)*584 + c*32     + quad*8];
            short8 kb1 = *(const short8*)&sbuf[(16+lq)*584 + (c+1)*32 + quad*8];
            s0a = __builtin_amdgcn_mfma_f32_16x16x32_bf16(ka0, qf[c],   s0a, 0, 0, 0);
            s1a = __builtin_amdgcn_mfma_f32_16x16x32_bf16(ka1, qf[c],   s1a, 0, 0, 0);
            s0b = __builtin_amdgcn_mfma_f32_16x16x32_bf16(kb0, qf[c+1], s0b, 0, 0, 0);
            s1b = __builtin_amdgcn_mfma_f32_16x16x32_bf16(kb1, qf[c+1], s1b, 0, 0, 0);
        }
        // online softmax (per-lane q-row = myq)
        float sv[8];
#pragma unroll
        for (int r = 0; r < 4; ++r) {
            int kk0 = k0 + quad*4 + r;
            sv[r]     = (kk0      <= myq) ? (s0a[r] + s0b[r]) * scale : -1e30f;
            sv[r + 4] = (kk0 + 16 <= myq) ? (s1a[r] + s1b[r]) * scale : -1e30f;
        }
        float mx = sv[0];
#pragma unroll
        for (int i = 1; i < 8; ++i) mx = fmaxf(mx, sv[i]);
        mx = fmaxf(mx, __shfl_xor(mx, 16));
        mx = fmaxf(mx, __shfl_xor(mx, 32));
        const float m_new = fmaxf(m_i, mx);
        const float alpha = __expf(m_i - m_new);
        float p[8]; float ls = 0.f;
#pragma unroll
        for (int i = 0; i < 8; ++i) { p[i] = __expf(sv[i] - m_new); ls += p[i]; }
        ls += __shfl_xor(ls, 16);
        ls += __shfl_xor(ls, 32);
        l_i = l_i * alpha + ls; m_i = m_new;
        if (__any(alpha < 1.0f)) {
#pragma unroll
            for (int i = 0; i < 32; ++i) {
                o[i][0]*=alpha; o[i][1]*=alpha; o[i][2]*=alpha; o[i][3]*=alpha;
            }
        }
        short8 pb = quad_transpose(pack2bf(p[0], p[1]), pack2bf(p[2], p[3]),
                                   pack2bf(p[4], p[5]), pack2bf(p[6], p[7]),
                                   srcA, srcB, lowq);
        __syncthreads();  // K-tile reads complete
        {   // Phase B stage: Vt rows (c) 0..511, cols k0..k0+31, unpadded [512][32]
#pragma unroll
            for (int p = 0; p < 8; ++p) {
                const unsigned short* vsrc =
                    vtb + (size_t)(p*64 + vrow) * S_ + k0 + vcol;
                async_copy16(vsrc, &sbuf[p*2048 + wv*512]);
            }
        }
        __syncthreads();  // (drains vmcnt)
        // PV
#pragma unroll
        for (int ct = 0; ct < 32; ++ct) {
            short8 va = *(const short8*)&sbuf[(ct*16 + lq)*32 + quad*8];
            o[ct] = __builtin_amdgcn_mfma_f32_16x16x32_bf16(va, pb, o[ct], 0, 0, 0);
        }
    }

    // epilogue: X @ out_absorb^T, bf16 out
    const float inv = 1.0f / l_i;
    f32x4 acc[8];
#pragma unroll
    for (int i = 0; i < 8; ++i) acc[i] = (f32x4){0.f, 0.f, 0.f, 0.f};
    const unsigned short* wrow = w2bf + ((size_t)h*256 + NOPE_ + lq) * RANK_ + quad*8;
#pragma unroll
    for (int ch = 0; ch < 16; ++ch) {
        short8 xa = quad_transpose(
            pack2bf(o[2*ch][0]*inv,   o[2*ch][1]*inv),
            pack2bf(o[2*ch][2]*inv,   o[2*ch][3]*inv),
            pack2bf(o[2*ch+1][0]*inv, o[2*ch+1][1]*inv),
            pack2bf(o[2*ch+1][2]*inv, o[2*ch+1][3]*inv),
            srcA, srcB, lowq);
#pragma unroll
        for (int dt = 0; dt < 8; ++dt) {
            short8 wf = *(const short8*)(wrow + (size_t)dt*16*RANK_ + ch*32);
            acc[dt] = __builtin_amdgcn_mfma_f32_16x16x32_bf16(xa, wf, acc[dt], 0, 0, 0);
        }
    }
    unsigned short* orow =
        attn_bf + ((size_t)b * S_ + q0 + wv*16 + quad*4) * (NH_*VDIM_) + h*VDIM_ + lq;
#pragma unroll
    for (int dt = 0; dt < 8; ++dt)
#pragma unroll
        for (int r = 0; r < 4; ++r)
            orow[(size_t)r * (NH_*VDIM_) + dt*16] = f2bf(acc[dt][r]);
}

extern "C" void kernel_launch(void* const* d_in, const int* in_sizes, int n_in,
                              void* d_out, int out_size, void* d_ws, size_t ws_size,
                              hipStream_t stream)
{
    const float* hidden  = (const float*)d_in[0];
    // d_in[1] = attention_mask (guaranteed causal tril, handled analytically)
    const int*   pos_ids = (const int*)d_in[2];
    const float* cosc    = (const float*)d_in[3];
    const float* sinc    = (const float*)d_in[4];
    const float* Wq      = (const float*)d_in[5];
    const float* Wkv_a   = (const float*)d_in[6];
    const float* lnw     = (const float*)d_in[7];
    const float* Wkv_b   = (const float*)d_in[8];
    const float* Wo      = (const float*)d_in[9];
    float* out = (float*)d_out;

    const int M = B_ * S_;  // 4096
    char* ws = (char*)d_ws;
    // Workspace layout (139.5 MB total, time-disjoint aliases):
    unsigned short* hidden_bf = (unsigned short*)ws;                 // 16.78 MB (live 1-5)
    unsigned short* wqaT      = (unsigned short*)ws;                 // alias (live 10-11)
    unsigned short* attn_bf   = (unsigned short*)ws;                 // alias (live 12-14)
    unsigned short* q_bf      = (unsigned short*)(ws + 16777216);    // 25.17 MB (live 3-11)
    unsigned short* ckv_bf    = (unsigned short*)(ws + 41943040);    // 4.72 MB (live 5-6)
    unsigned short* vt        = ckv_bf;                              // alias (live 8-12)
    unsigned short* q_cat     = (unsigned short*)(ws + 46661632);    // 75.50 MB (live 7-12)
    unsigned short* k_cat     = (unsigned short*)(ws + 122159104);   // 4.72 MB (live 6-12)
    unsigned short* wT        = (unsigned short*)(ws + 126877696);   // 12.58 MB (WqT/WkvaT/WoT)
    unsigned short* w2bf      = (unsigned short*)(ws + 126877696 + 8388608); // 4.19 MB (live 9-12)

    // 1. hidden -> bf16
    cast_bf16<<<8192, 256, 0, stream>>>(hidden, hidden_bf);
    // 2. WqT = Wq^T bf16 [3072][2048]
    transpose_w<<<dim3(32, 48, 1), 256, 0, stream>>>(Wq, wT, H_, NH_*QHD_, 0, 0);
    // 3. q_bf = hidden @ Wq (bf16 out)
    bgemm2<<<dim3(24, 32, 1), 256, 0, stream>>>(hidden_bf, H_, wT, q_bf, NH_*QHD_, H_, NH_*QHD_, 0);
    // 4. WkvaT bf16 [576][2048]
    transpose_w<<<dim3(32, 9, 1), 256, 0, stream>>>(Wkv_a, wT, H_, DTOT_, 0, 0);
    // 5. ckv_bf = hidden @ Wkv_a (bf16 out, ragged N=576)
    bgemm2<<<dim3(5, 32, 1), 256, 0, stream>>>(hidden_bf, H_, wT, ckv_bf, DTOT_, H_, DTOT_, 0);
    // 6. RMSNorm + k_pe RoPE -> k_cat
    postkv<<<M, 128, 0, stream>>>(ckv_bf, lnw, pos_ids, cosc, sinc, k_cat);
    // 7. q_pe RoPE -> q_cat[...,512:576]
    ropeq<<<M, 512, 0, stream>>>(q_bf, pos_ids, cosc, sinc, q_cat);
    // 8. Vt = transpose of k_cat[:, :512]
    transpose_v<<<dim3(S_/64, RANK_/64, B_), 256, 0, stream>>>(k_cat, vt);
    // 9. Wkv_b -> bf16 (flash epilogue weights)
    wcast<<<(NH_*256*RANK_)/1024, 256, 0, stream>>>(Wkv_b, w2bf);
    // 10. wqaT[h] = (Wkv_b[h][0:128])^T bf16 [512][128]
    transpose_w<<<dim3(2, 8, 16), 256, 0, stream>>>(Wkv_b, wqaT, NOPE_, RANK_,
                                                    (size_t)256*RANK_, (size_t)RANK_*NOPE_);
    // 11. q_cat[...,0:512] = q_nope @ q_absorb (batched, K=128)
    bgemm2<<<dim3(4, 16, 32), 256, 0, stream>>>(q_bf, NH_*QHD_, wqaT, q_cat, DTOT_, NOPE_, RANK_, 1);
    // 12. flash attention -> attn_bf (bf16)
    flash_attn3<<<dim3(NH_, S_/64, B_), 256, 0, stream>>>(q_cat, k_cat, vt, w2bf, attn_bf);
    // 13. WoT bf16 [2048][2048]
    transpose_w<<<dim3(32, 32, 1), 256, 0, stream>>>(Wo, wT, H_, H_, 0, 0);
    // 14. out = attn @ Wo (f32 out)
    bgemm2f<<<dim3(16, 32, 1), 256, 0, stream>>>(attn_bf, H_, wT, out, H_, H_, H_);
}

// Round 5
// 637.191 us; speedup vs baseline: 46.6043x; 1.0451x over previous
//
#include <hip/hip_runtime.h>
#include <math.h>

#define B_    2
#define S_    2048
#define H_    2048
#define NH_   16
#define NOPE_ 128
#define ROPE_ 64
#define VDIM_ 128
#define RANK_ 512
#define QHD_  192   // NOPE + ROPE
#define DTOT_ 576   // RANK + ROPE

typedef short short8 __attribute__((ext_vector_type(8)));
typedef float f32x4 __attribute__((ext_vector_type(4)));

__device__ __forceinline__ unsigned short f2bf(float f) {
    unsigned u = __float_as_uint(f);
    u += 0x7fffu + ((u >> 16) & 1u);
    return (unsigned short)(u >> 16);
}
__device__ __forceinline__ float bf2f(unsigned short u) {
    return __uint_as_float((unsigned)u << 16);
}
__device__ __forceinline__ unsigned pack2bf(float a, float b) {
    return (unsigned)f2bf(a) | ((unsigned)f2bf(b) << 16);
}
__device__ __forceinline__ unsigned long long pack4bf(float a, float b, float c, float d) {
    return (unsigned long long)pack2bf(a, b) | ((unsigned long long)pack2bf(c, d) << 32);
}
union i4s8 { int4 i; short8 s; };

// Async global->LDS, 16B per lane. LDS dest = wave-uniform base + lane*16.
typedef __attribute__((address_space(3))) unsigned int lds_u32_t;
typedef __attribute__((address_space(1))) const unsigned int glob_u32_t;
__device__ __forceinline__ void async_copy16(const unsigned short* g, unsigned short* l) {
    __builtin_amdgcn_global_load_lds((glob_u32_t*)g, (lds_u32_t*)l, 16, 0, 0);
}

// ---------------------------------------------------------------------------
// cast fp32 -> bf16, 4 elems/thread.
// ---------------------------------------------------------------------------
__global__ __launch_bounds__(256) void cast_bf16(const float* __restrict__ in,
                                                 unsigned short* __restrict__ out)
{
    const size_t i = ((size_t)blockIdx.x * 256 + threadIdx.x) * 4;
    float4 v = *(const float4*)(in + i);
    *(unsigned long long*)(out + i) = pack4bf(v.x, v.y, v.z, v.w);
}

// ---------------------------------------------------------------------------
// Transpose + cast: in fp32 [Rr][Cc] (batched) -> out bf16 [Cc][Rr].
// grid (Rr/64, Cc/64, batch), 256 threads.
// ---------------------------------------------------------------------------
__global__ __launch_bounds__(256) void transpose_w(const float* __restrict__ in,
                                                   unsigned short* __restrict__ out,
                                                   int Rr, int Cc,
                                                   size_t inBatch, size_t outBatch)
{
    __shared__ unsigned short tl[64][72];
    in  += (size_t)blockIdx.z * inBatch;
    out += (size_t)blockIdx.z * outBatch;
    const int t  = threadIdx.x;
    const int r0 = blockIdx.x * 64;
    const int c0 = blockIdx.y * 64;
    const int lr = t >> 4;
    const int lc = (t & 15) * 4;
#pragma unroll
    for (int r = 0; r < 4; ++r) {
        float4 v = *(const float4*)(in + (size_t)(r0 + lr*4 + r) * Cc + c0 + lc);
        tl[lr*4 + r][lc+0] = f2bf(v.x); tl[lr*4 + r][lc+1] = f2bf(v.y);
        tl[lr*4 + r][lc+2] = f2bf(v.z); tl[lr*4 + r][lc+3] = f2bf(v.w);
    }
    __syncthreads();
#pragma unroll
    for (int r = 0; r < 4; ++r) {
        ushort4 v;
        v.x = tl[lc+0][lr*4+r]; v.y = tl[lc+1][lr*4+r];
        v.z = tl[lc+2][lr*4+r]; v.w = tl[lc+3][lr*4+r];
        *(ushort4*)(out + (size_t)(c0 + lr*4 + r) * Rr + r0 + lc) = v;
    }
}

// ---------------------------------------------------------------------------
// bf16 MFMA GEMM, m97-style: C = A[M][K](lda) @ Bt^T, Bt bf16 [N][K].
// 128x128 tile, 4 waves, BK=32, global_load_lds staging. N-guard for ragged N.
// ---------------------------------------------------------------------------
#define BGEMM_BODY(STORE_STMT)                                                     \
    __shared__ unsigned short Al[128*32];                                          \
    __shared__ unsigned short Bl[128*32];                                          \
    const int t = threadIdx.x;                                                     \
    const int wv = t >> 6;                                                         \
    const int lane = t & 63;                                                       \
    const int lq = lane & 15, quad = lane >> 4;                                    \
    const int m0 = blockIdx.y * 128, n0 = blockIdx.x * 128;                        \
    const int wrow = (wv >> 1) * 64, wcol = (wv & 1) * 64;                         \
    const int srow = lane >> 2;                                                    \
    const int scol = (lane & 3) * 8;                                               \
    f32x4 acc[4][4] = {};                                                          \
    for (int k0 = 0; k0 < K; k0 += 32) {                                           \
        _Pragma("unroll")                                                          \
        for (int pA = 0; pA < 2; ++pA) {                                           \
            const unsigned short* src =                                            \
                A + (size_t)(m0 + pA*64 + wv*16 + srow) * lda + k0 + scol;         \
            async_copy16(src, &Al[pA*2048 + wv*512]);                              \
        }                                                                          \
        _Pragma("unroll")                                                          \
        for (int pB = 0; pB < 2; ++pB) {                                           \
            int brow = n0 + pB*64 + wv*16 + srow;                                  \
            if (brow > N - 1) brow = N - 1;                                        \
            const unsigned short* src = B + (size_t)brow * K + k0 + scol;          \
            async_copy16(src, &Bl[pB*2048 + wv*512]);                              \
        }                                                                          \
        __syncthreads();                                                           \
        short8 af[4], bf[4];                                                       \
        _Pragma("unroll")                                                          \
        for (int i = 0; i < 4; ++i) {                                              \
            af[i] = *(const short8*)&Al[(wrow + i*16 + lq)*32 + quad*8];           \
            bf[i] = *(const short8*)&Bl[(wcol + i*16 + lq)*32 + quad*8];           \
        }                                                                          \
        _Pragma("unroll")                                                          \
        for (int mi = 0; mi < 4; ++mi)                                             \
            _Pragma("unroll")                                                      \
            for (int ni = 0; ni < 4; ++ni)                                         \
                acc[mi][ni] = __builtin_amdgcn_mfma_f32_16x16x32_bf16(             \
                    af[mi], bf[ni], acc[mi][ni], 0, 0, 0);                         \
        __syncthreads();                                                           \
    }                                                                              \
    _Pragma("unroll")                                                              \
    for (int mi = 0; mi < 4; ++mi)                                                 \
        _Pragma("unroll")                                                          \
        for (int ni = 0; ni < 4; ++ni) {                                           \
            int col = n0 + wcol + ni*16 + lq;                                      \
            if (col < N) {                                                         \
                _Pragma("unroll")                                                  \
                for (int r = 0; r < 4; ++r)                                        \
                    STORE_STMT;                                                    \
            }                                                                      \
        }

__global__ __launch_bounds__(256, 2) void bgemm2(const unsigned short* __restrict__ A,
                                                 int lda,
                                                 const unsigned short* __restrict__ B,
                                                 unsigned short* __restrict__ C,
                                                 int ldc, int K, int N, int qcmode)
{
    if (qcmode) {
        const int z = blockIdx.z;
        A += (size_t)(z >> 4) * S_ * (NH_*QHD_) + (z & 15) * QHD_;
        B += (size_t)(z & 15) * RANK_ * NOPE_;
        C += (size_t)z * S_ * DTOT_;
    }
    BGEMM_BODY(C[(size_t)(m0 + wrow + mi*16 + quad*4 + r) * ldc + col] = f2bf(acc[mi][ni][r]))
}

__global__ __launch_bounds__(256, 2) void bgemm2f(const unsigned short* __restrict__ A,
                                                  int lda,
                                                  const unsigned short* __restrict__ B,
                                                  float* __restrict__ C,
                                                  int ldc, int K, int N)
{
    BGEMM_BODY(C[(size_t)(m0 + wrow + mi*16 + quad*4 + r) * ldc + col] = acc[mi][ni][r])
}

// ---------------------------------------------------------------------------
// Per (b,s) row: RMSNorm ckv (bf16 in) -> k_cat[0:512]; RoPE k_pe -> [512:576].
// ---------------------------------------------------------------------------
__global__ __launch_bounds__(128) void postkv(const unsigned short* __restrict__ ckv_bf,
                                              const float* __restrict__ lnw,
                                              const int*   __restrict__ pos_ids,
                                              const float* __restrict__ cosc,
                                              const float* __restrict__ sinc,
                                              unsigned short* __restrict__ k_cat)
{
    const int row = blockIdx.x;
    const int t   = threadIdx.x;
    const unsigned short* src = ckv_bf + (size_t)row * DTOT_;
    __shared__ float red[128];

    ushort4 v = *(const ushort4*)(src + t * 4);
    float x0 = bf2f(v.x), x1 = bf2f(v.y), x2 = bf2f(v.z), x3 = bf2f(v.w);
    red[t] = x0*x0 + x1*x1 + x2*x2 + x3*x3;
    __syncthreads();
    for (int off = 64; off > 0; off >>= 1) {
        if (t < off) red[t] += red[t + off];
        __syncthreads();
    }
    const float rs = rsqrtf(red[0] / (float)RANK_ + 1e-6f);

    unsigned short* kc = k_cat + (size_t)row * DTOT_;
    *(unsigned long long*)(kc + t*4) =
        pack4bf(x0*rs*lnw[t*4+0], x1*rs*lnw[t*4+1], x2*rs*lnw[t*4+2], x3*rs*lnw[t*4+3]);

    if (t < 32) {
        const int pos = pos_ids[row];
        const float c  = cosc[pos * ROPE_ + t];
        const float sn = sinc[pos * ROPE_ + t];
        const float y0 = bf2f(src[RANK_ + 2*t]);
        const float y1 = bf2f(src[RANK_ + 2*t + 1]);
        kc[RANK_ + t]      = f2bf(y0*c - y1*sn);
        kc[RANK_ + 32 + t] = f2bf(y1*c + y0*sn);
    }
}

// ---------------------------------------------------------------------------
// RoPE q_pe (bf16 in) -> q_cat[...,512:576]. grid = B*S, 512 threads.
// ---------------------------------------------------------------------------
__global__ __launch_bounds__(512) void ropeq(const unsigned short* __restrict__ q_bf,
                                             const int*   __restrict__ pos_ids,
                                             const float* __restrict__ cosc,
                                             const float* __restrict__ sinc,
                                             unsigned short* __restrict__ q_cat)
{
    const int row = blockIdx.x;
    const int t   = threadIdx.x;
    const int h   = t >> 5;
    const int i   = t & 31;
    const int pos = pos_ids[row];
    const float c  = cosc[pos * ROPE_ + i];
    const float sn = sinc[pos * ROPE_ + i];
    const unsigned short* qrow = q_bf + (size_t)row * (NH_*QHD_) + h * QHD_ + NOPE_;
    const float x0 = bf2f(qrow[2*i]);
    const float x1 = bf2f(qrow[2*i + 1]);
    const int b = row >> 11, s = row & 2047;
    unsigned short* qc = q_cat + ((size_t)(b * NH_ + h) * S_ + s) * DTOT_ + RANK_;
    qc[i]      = f2bf(x0*c - x1*sn);
    qc[32 + i] = f2bf(x1*c + x0*sn);
}

// ---------------------------------------------------------------------------
// Vt[b,c,k] = k_cat[b,k,c] for c<512. grid (32, 8, 2).
// ---------------------------------------------------------------------------
__global__ __launch_bounds__(256) void transpose_v(const unsigned short* __restrict__ k_cat,
                                                   unsigned short* __restrict__ vt)
{
    __shared__ unsigned short tl[64][72];
    const int t  = threadIdx.x;
    const int k0 = blockIdx.x * 64;
    const int c0 = blockIdx.y * 64;
    const int b  = blockIdx.z;
    const int lr = t >> 4;
    const int lc = (t & 15) * 4;
#pragma unroll
    for (int r = 0; r < 4; ++r) {
        ushort4 v = *(const ushort4*)(k_cat + ((size_t)b * S_ + k0 + lr*4 + r) * DTOT_ + c0 + lc);
        tl[lr*4 + r][lc+0] = v.x; tl[lr*4 + r][lc+1] = v.y;
        tl[lr*4 + r][lc+2] = v.z; tl[lr*4 + r][lc+3] = v.w;
    }
    __syncthreads();
#pragma unroll
    for (int r = 0; r < 4; ++r) {
        ushort4 v;
        v.x = tl[lc+0][lr*4+r]; v.y = tl[lc+1][lr*4+r];
        v.z = tl[lc+2][lr*4+r]; v.w = tl[lc+3][lr*4+r];
        *(ushort4*)(vt + ((size_t)b * RANK_ + c0 + lr*4 + r) * S_ + k0 + lc) = v;
    }
}

__global__ __launch_bounds__(256) void wcast(const float* __restrict__ w,
                                             unsigned short* __restrict__ wbf)
{
    const size_t i = ((size_t)blockIdx.x * 256 + threadIdx.x) * 4;
    float4 v = *(const float4*)(w + i);
    *(unsigned long long*)(wbf + i) = pack4bf(v.x, v.y, v.z, v.w);
}

// ---------------------------------------------------------------------------
// Flash attention v4: 4 waves/block, 64 q-rows, 2 barriers/tile.
// K-tile [32][584] manual-staged (conflict-free stride); V-tile [512][32] via
// global_load_lds issued EARLY (hidden behind QK) with XOR-swizzled source
// (4-way instead of 8-way bank conflicts on PV reads).
// ---------------------------------------------------------------------------
__device__ __forceinline__ short8 quad_transpose(unsigned d0, unsigned d1,
                                                 unsigned d2, unsigned d3,
                                                 int srcA, int srcB, bool lowquad)
{
    int e0 = __shfl((int)d0, srcA, 64);
    int e1 = __shfl((int)d1, srcA, 64);
    int e2 = __shfl((int)d2, srcA, 64);
    int e3 = __shfl((int)d3, srcA, 64);
    int f0 = __shfl((int)d0, srcB, 64);
    int f1 = __shfl((int)d1, srcB, 64);
    int f2 = __shfl((int)d2, srcB, 64);
    int f3 = __shfl((int)d3, srcB, 64);
    i4s8 u;
    u.i.x = lowquad ? e0 : e2;
    u.i.y = lowquad ? e1 : e3;
    u.i.z = lowquad ? f0 : f2;
    u.i.w = lowquad ? f1 : f3;
    return u.s;
}

__global__ __launch_bounds__(256, 2) void flash_attn4(
    const unsigned short* __restrict__ q_cat,
    const unsigned short* __restrict__ k_cat,
    const unsigned short* __restrict__ vt,
    const unsigned short* __restrict__ w2bf,
    unsigned short* __restrict__ attn_bf)
{
    __shared__ unsigned short sK[32*584];    // 37376 B, conflict-balanced stride
    __shared__ unsigned short sV[512*32];    // 32768 B, XOR-swizzled contents

    const int t    = threadIdx.x;
    const int wv   = t >> 6;
    const int lane = t & 63;
    const int lq   = lane & 15;
    const int quad = lane >> 4;
    const int h    = blockIdx.x;
    const int q0   = (31 - blockIdx.y) * 64;   // longest strips first
    const int b    = blockIdx.z;
    const int srcA = lq + ((quad & 1) << 5);
    const int srcB = srcA + 16;
    const bool lowq = quad < 2;
    const int myq  = q0 + wv*16 + lq;

    // Q fragments (loop-invariant)
    const unsigned short* qrow =
        q_cat + (((size_t)(b*NH_ + h)) * S_ + q0 + wv*16 + lq) * DTOT_ + quad*8;
    short8 qf[18];
#pragma unroll
    for (int c = 0; c < 18; ++c) qf[c] = *(const short8*)(qrow + c*32);

    const unsigned short* kcb = k_cat + (size_t)b * S_ * DTOT_;
    const unsigned short* vtb = vt    + (size_t)b * RANK_ * S_;

    f32x4 o[32];
#pragma unroll
    for (int i = 0; i < 32; ++i) o[i] = (f32x4){0.f, 0.f, 0.f, 0.f};
    float m_i = -1e30f, l_i = 0.f;
    const float scale = 0.0721687836f;  // 1/sqrt(192)
    const int ntiles = (q0 >> 5) + 2;

    // staging coords
    const int krow = t >> 3;                       // 0..31
    const int kcol = (t & 7) * 8;                  // shorts
    const int vrow = wv*16 + (lane >> 2);          // + p*64
    const int vgcol = (((lane & 3) ^ ((lane >> 2) & 3))) * 8;  // XOR-swizzled group
    const int pvsw = (quad ^ (lq & 3)) * 8;        // PV read group
    unsigned short* ldsK = &sK[krow*584 + kcol];

    for (int tt = 0; tt < ntiles; ++tt) {
        const int k0 = tt << 5;
        {   // K stage: load + write (Kbuf free: QK(t-1) reads done pre-barrier2)
            const unsigned short* ksrc = kcb + (size_t)(k0 + krow) * DTOT_ + kcol;
#pragma unroll 3
            for (int p = 0; p < 9; ++p)
                *(short8*)(ldsK + p*64) = *(const short8*)(ksrc + p*64);
        }
        __syncthreads();   // barrier1: K visible; Vbuf free (all PV(t-1) done)
        {   // V stage: issue DMA EARLY — latency hidden behind QK+softmax
#pragma unroll
            for (int p = 0; p < 8; ++p) {
                const unsigned short* vsrc =
                    vtb + (size_t)(p*64 + vrow) * S_ + k0 + vgcol;
                async_copy16(vsrc, &sV[p*2048 + wv*512]);
            }
        }
        // QK^T
        f32x4 s0a = {0.f,0.f,0.f,0.f}, s0b = {0.f,0.f,0.f,0.f};
        f32x4 s1a = {0.f,0.f,0.f,0.f}, s1b = {0.f,0.f,0.f,0.f};
#pragma unroll
        for (int c = 0; c < 18; c += 2) {
            short8 ka0 = *(const short8*)&sK[lq*584      + c*32     + quad*8];
            short8 kb0 = *(const short8*)&sK[lq*584      + (c+1)*32 + quad*8];
            short8 ka1 = *(const short8*)&sK[(16+lq)*584 + c*32     + quad*8];
            short8 kb1 = *(const short8*)&sK[(16+lq)*584 + (c+1)*32 + quad*8];
            s0a = __builtin_amdgcn_mfma_f32_16x16x32_bf16(ka0, qf[c],   s0a, 0, 0, 0);
            s1a = __builtin_amdgcn_mfma_f32_16x16x32_bf16(ka1, qf[c],   s1a, 0, 0, 0);
            s0b = __builtin_amdgcn_mfma_f32_16x16x32_bf16(kb0, qf[c+1], s0b, 0, 0, 0);
            s1b = __builtin_amdgcn_mfma_f32_16x16x32_bf16(kb1, qf[c+1], s1b, 0, 0, 0);
        }
        // online softmax (per-lane q-row = myq)
        float sv[8];
#pragma unroll
        for (int r = 0; r < 4; ++r) {
            int kk0 = k0 + quad*4 + r;
            sv[r]     = (kk0      <= myq) ? (s0a[r] + s0b[r]) * scale : -1e30f;
            sv[r + 4] = (kk0 + 16 <= myq) ? (s1a[r] + s1b[r]) * scale : -1e30f;
        }
        float mx = sv[0];
#pragma unroll
        for (int i = 1; i < 8; ++i) mx = fmaxf(mx, sv[i]);
        mx = fmaxf(mx, __shfl_xor(mx, 16));
        mx = fmaxf(mx, __shfl_xor(mx, 32));
        const float m_new = fmaxf(m_i, mx);
        const float alpha = __expf(m_i - m_new);
        float p[8]; float ls = 0.f;
#pragma unroll
        for (int i = 0; i < 8; ++i) { p[i] = __expf(sv[i] - m_new); ls += p[i]; }
        ls += __shfl_xor(ls, 16);
        ls += __shfl_xor(ls, 32);
        l_i = l_i * alpha + ls; m_i = m_new;
        if (__any(alpha < 1.0f)) {
#pragma unroll
            for (int i = 0; i < 32; ++i) {
                o[i][0]*=alpha; o[i][1]*=alpha; o[i][2]*=alpha; o[i][3]*=alpha;
            }
        }
        short8 pb = quad_transpose(pack2bf(p[0], p[1]), pack2bf(p[2], p[3]),
                                   pack2bf(p[4], p[5]), pack2bf(p[6], p[7]),
                                   srcA, srcB, lowq);
        __syncthreads();   // barrier2: drains V DMA; K-tile reads complete
        // PV (swizzled reads: 4-way max conflict)
#pragma unroll
        for (int ct = 0; ct < 32; ++ct) {
            short8 va = *(const short8*)&sV[(ct*16 + lq)*32 + pvsw];
            o[ct] = __builtin_amdgcn_mfma_f32_16x16x32_bf16(va, pb, o[ct], 0, 0, 0);
        }
    }

    // epilogue: X @ out_absorb^T, bf16 out
    const float inv = 1.0f / l_i;
    f32x4 acc[8];
#pragma unroll
    for (int i = 0; i < 8; ++i) acc[i] = (f32x4){0.f, 0.f, 0.f, 0.f};
    const unsigned short* wrow = w2bf + ((size_t)h*256 + NOPE_ + lq) * RANK_ + quad*8;
#pragma unroll
    for (int ch = 0; ch < 16; ++ch) {
        short8 xa = quad_transpose(
            pack2bf(o[2*ch][0]*inv,   o[2*ch][1]*inv),
            pack2bf(o[2*ch][2]*inv,   o[2*ch][3]*inv),
            pack2bf(o[2*ch+1][0]*inv, o[2*ch+1][1]*inv),
            pack2bf(o[2*ch+1][2]*inv, o[2*ch+1][3]*inv),
            srcA, srcB, lowq);
#pragma unroll
        for (int dt = 0; dt < 8; ++dt) {
            short8 wf = *(const short8*)(wrow + (size_t)dt*16*RANK_ + ch*32);
            acc[dt] = __builtin_amdgcn_mfma_f32_16x16x32_bf16(xa, wf, acc[dt], 0, 0, 0);
        }
    }
    unsigned short* orow =
        attn_bf + ((size_t)b * S_ + q0 + wv*16 + quad*4) * (NH_*VDIM_) + h*VDIM_ + lq;
#pragma unroll
    for (int dt = 0; dt < 8; ++dt)
#pragma unroll
        for (int r = 0; r < 4; ++r)
            orow[(size_t)r * (NH_*VDIM_) + dt*16] = f2bf(acc[dt][r]);
}

extern "C" void kernel_launch(void* const* d_in, const int* in_sizes, int n_in,
                              void* d_out, int out_size, void* d_ws, size_t ws_size,
                              hipStream_t stream)
{
    const float* hidden  = (const float*)d_in[0];
    // d_in[1] = attention_mask (guaranteed causal tril, handled analytically)
    const int*   pos_ids = (const int*)d_in[2];
    const float* cosc    = (const float*)d_in[3];
    const float* sinc    = (const float*)d_in[4];
    const float* Wq      = (const float*)d_in[5];
    const float* Wkv_a   = (const float*)d_in[6];
    const float* lnw     = (const float*)d_in[7];
    const float* Wkv_b   = (const float*)d_in[8];
    const float* Wo      = (const float*)d_in[9];
    float* out = (float*)d_out;

    const int M = B_ * S_;  // 4096
    char* ws = (char*)d_ws;
    // Workspace layout (139.5 MB total, time-disjoint aliases):
    unsigned short* hidden_bf = (unsigned short*)ws;                 // 16.78 MB (live 1-5)
    unsigned short* wqaT      = (unsigned short*)ws;                 // alias (live 10-11)
    unsigned short* attn_bf   = (unsigned short*)ws;                 // alias (live 12-14)
    unsigned short* q_bf      = (unsigned short*)(ws + 16777216);    // 25.17 MB (live 3-11)
    unsigned short* ckv_bf    = (unsigned short*)(ws + 41943040);    // 4.72 MB (live 5-6)
    unsigned short* vt        = ckv_bf;                              // alias (live 8-12)
    unsigned short* q_cat     = (unsigned short*)(ws + 46661632);    // 75.50 MB (live 7-12)
    unsigned short* k_cat     = (unsigned short*)(ws + 122159104);   // 4.72 MB (live 6-12)
    unsigned short* wT        = (unsigned short*)(ws + 126877696);   // 12.58 MB (WqT/WkvaT/WoT)
    unsigned short* w2bf      = (unsigned short*)(ws + 126877696 + 8388608); // 4.19 MB (live 9-12)

    // 1. hidden -> bf16
    cast_bf16<<<8192, 256, 0, stream>>>(hidden, hidden_bf);
    // 2. WqT = Wq^T bf16 [3072][2048]
    transpose_w<<<dim3(32, 48, 1), 256, 0, stream>>>(Wq, wT, H_, NH_*QHD_, 0, 0);
    // 3. q_bf = hidden @ Wq (bf16 out)
    bgemm2<<<dim3(24, 32, 1), 256, 0, stream>>>(hidden_bf, H_, wT, q_bf, NH_*QHD_, H_, NH_*QHD_, 0);
    // 4. WkvaT bf16 [576][2048]
    transpose_w<<<dim3(32, 9, 1), 256, 0, stream>>>(Wkv_a, wT, H_, DTOT_, 0, 0);
    // 5. ckv_bf = hidden @ Wkv_a (bf16 out, ragged N=576)
    bgemm2<<<dim3(5, 32, 1), 256, 0, stream>>>(hidden_bf, H_, wT, ckv_bf, DTOT_, H_, DTOT_, 0);
    // 6. RMSNorm + k_pe RoPE -> k_cat
    postkv<<<M, 128, 0, stream>>>(ckv_bf, lnw, pos_ids, cosc, sinc, k_cat);
    // 7. q_pe RoPE -> q_cat[...,512:576]
    ropeq<<<M, 512, 0, stream>>>(q_bf, pos_ids, cosc, sinc, q_cat);
    // 8. Vt = transpose of k_cat[:, :512]
    transpose_v<<<dim3(S_/64, RANK_/64, B_), 256, 0, stream>>>(k_cat, vt);
    // 9. Wkv_b -> bf16 (flash epilogue weights)
    wcast<<<(NH_*256*RANK_)/1024, 256, 0, stream>>>(Wkv_b, w2bf);
    // 10. wqaT[h] = (Wkv_b[h][0:128])^T bf16 [512][128]
    transpose_w<<<dim3(2, 8, 16), 256, 0, stream>>>(Wkv_b, wqaT, NOPE_, RANK_,
                                                    (size_t)256*RANK_, (size_t)RANK_*NOPE_);
    // 11. q_cat[...,0:512] = q_nope @ q_absorb (batched, K=128)
    bgemm2<<<dim3(4, 16, 32), 256, 0, stream>>>(q_bf, NH_*QHD_, wqaT, q_cat, DTOT_, NOPE_, RANK_, 1);
    // 12. flash attention -> attn_bf (bf16)
    flash_attn4<<<dim3(NH_, S_/64, B_), 256, 0, stream>>>(q_cat, k_cat, vt, w2bf, attn_bf);
    // 13. WoT bf16 [2048][2048]
    transpose_w<<<dim3(32, 32, 1), 256, 0, stream>>>(Wo, wT, H_, H_, 0, 0);
    // 14. out = attn @ Wo (f32 out)
    bgemm2f<<<dim3(16, 32, 1), 256, 0, stream>>>(attn_bf, H_, wT, out, H_, H_, H_);
}